// Round 1
// baseline (306.209 us; speedup 1.0000x reference)
//
#include <hip/hip_runtime.h>

#define R_ 32
#define DA_ 32
#define DO_ 32
#define DAR_ 16
#define DOR_ 16
#define NTRAJ 256
#define TSTEPS 128
#define PDIM 17           // 16 raw dims + bias
#define KTRUE 289         // 17*17
#define KPAD 320          // padded K (mult of 32), C pad rows zeroed
#define MDIM 1024         // (i,l) = R*R
#define BM 128
#define BN 128
#define KC 32

// ---------------------------------------------------------------------------
// D[i,p,k,l] = sum_j Wa'[p,j] * A[i,j,k,l]      (Wa' row 16 = ba)
// ---------------------------------------------------------------------------
__global__ void build_D(const float* __restrict__ A, const float* __restrict__ Wa,
                        const float* __restrict__ ba, float* __restrict__ D) {
  int id = blockIdx.x * blockDim.x + threadIdx.x;
  if (id >= R_ * PDIM * DO_ * R_) return;
  int l = id & 31;
  int k = (id >> 5) & 31;
  int p = (id >> 10) % PDIM;
  int i = id / (PDIM * 1024);
  // A[i,j,k,l] flat = i*32768 + j*1024 + k*32 + l
  const float* Ab = A + (size_t)i * 32768 + k * 32 + l;
  float s = 0.f;
  if (p < DAR_) {
    const float* w = Wa + p * DA_;
#pragma unroll 8
    for (int j = 0; j < DA_; ++j) s += w[j] * Ab[j * 1024];
  } else {
#pragma unroll 8
    for (int j = 0; j < DA_; ++j) s += ba[j] * Ab[j * 1024];
  }
  D[id] = s;  // D flat = i*17408 + p*1024 + k*32 + l
}

// ---------------------------------------------------------------------------
// C[pq, il] = sum_k Wo'[q,k] * D[i,p,k,l];  rows pq in [289,320) zeroed
// ---------------------------------------------------------------------------
__global__ void build_C(const float* __restrict__ D, const float* __restrict__ Wo,
                        const float* __restrict__ bo, float* __restrict__ C) {
  int id = blockIdx.x * blockDim.x + threadIdx.x;
  if (id >= KPAD * MDIM) return;
  int il = id & 1023;
  int pq = id >> 10;
  if (pq >= KTRUE) { C[id] = 0.f; return; }
  int p = pq / PDIM, q = pq % PDIM;
  int i = il >> 5, l = il & 31;
  const float* Db = D + (size_t)(i * PDIM + p) * 1024 + l;  // k stride 32
  float s = 0.f;
  if (q < DOR_) {
    const float* w = Wo + q * DO_;
#pragma unroll 8
    for (int k = 0; k < DO_; ++k) s += w[k] * Db[k * 32];
  } else {
#pragma unroll 8
    for (int k = 0; k < DO_; ++k) s += bo[k] * Db[k * 32];
  }
  C[id] = s;
}

// ---------------------------------------------------------------------------
// Zt[pq][nt] = act'[p] * obs'[q]   (pre-transposed: rows K, cols NT-chunk)
// ---------------------------------------------------------------------------
__global__ void build_Zt(const float* __restrict__ actions, const float* __restrict__ obss,
                         float* __restrict__ Zt, int n0, int NTc) {
  int nt = blockIdx.x * blockDim.x + threadIdx.x;
  if (nt >= NTc) return;
  int gnt = n0 * TSTEPS + nt;  // chunk is contiguous trajectories
  const float4* ap = (const float4*)(actions + (size_t)gnt * DAR_);
  const float4* op = (const float4*)(obss + (size_t)gnt * DOR_);
  float av[PDIM], ov[PDIM];
#pragma unroll
  for (int m = 0; m < 4; ++m) {
    float4 x = ap[m];
    av[m * 4 + 0] = x.x; av[m * 4 + 1] = x.y; av[m * 4 + 2] = x.z; av[m * 4 + 3] = x.w;
    float4 y = op[m];
    ov[m * 4 + 0] = y.x; ov[m * 4 + 1] = y.y; ov[m * 4 + 2] = y.z; ov[m * 4 + 3] = y.w;
  }
  av[16] = 1.f; ov[16] = 1.f;
#pragma unroll
  for (int p = 0; p < PDIM; ++p) {
#pragma unroll
    for (int q = 0; q < PDIM; ++q) {
      Zt[(size_t)(p * PDIM + q) * NTc + nt] = av[p] * ov[q];
    }
  }
  // rows [289,320) of Zt never written: C pad rows are 0, product is 0 anyway
}

// ---------------------------------------------------------------------------
// M[nt, il] = sum_k Zt[k][nt] * C[k][il]   fp32 tiled GEMM, 128x128, 8x8/thread
// ---------------------------------------------------------------------------
__global__ __launch_bounds__(256) void gemm_M(const float* __restrict__ Zt,
                                              const float* __restrict__ C,
                                              float* __restrict__ M, int NTc) {
  __shared__ float Zs[KC][BM];
  __shared__ float Cs[KC][BN];
  const int bm = blockIdx.x * BM;
  const int bn = blockIdx.y * BN;
  const int tid = threadIdx.x;
  const int tr = tid >> 4, tc = tid & 15;
  const int r0 = tr * 8, c0 = tc * 8;
  float acc[8][8] = {};

  for (int kc = 0; kc < KPAD; kc += KC) {
#pragma unroll
    for (int m = 0; m < 4; ++m) {
      int e = tid + m * 256;        // 1024 float4 units per buffer
      int k = e >> 5;               // 32 float4 per 128-float row
      int r4 = (e & 31) << 2;
      *(float4*)&Zs[k][r4] = *(const float4*)&Zt[(size_t)(kc + k) * NTc + bm + r4];
      *(float4*)&Cs[k][r4] = *(const float4*)&C[(size_t)(kc + k) * MDIM + bn + r4];
    }
    __syncthreads();
#pragma unroll
    for (int k = 0; k < KC; ++k) {
      float za[8], cb[8];
      *(float4*)&za[0] = *(const float4*)&Zs[k][r0];
      *(float4*)&za[4] = *(const float4*)&Zs[k][r0 + 4];
      *(float4*)&cb[0] = *(const float4*)&Cs[k][c0];
      *(float4*)&cb[4] = *(const float4*)&Cs[k][c0 + 4];
#pragma unroll
      for (int x = 0; x < 8; ++x)
#pragma unroll
        for (int y = 0; y < 8; ++y) acc[x][y] += za[x] * cb[y];
    }
    __syncthreads();
  }
#pragma unroll
  for (int x = 0; x < 8; ++x) {
    float* mp = M + (size_t)(bm + r0 + x) * MDIM + bn + c0;
    *(float4*)&mp[0] = *(float4*)&acc[x][0];
    *(float4*)&mp[4] = *(float4*)&acc[x][4];
  }
}

// ---------------------------------------------------------------------------
// Scan: per trajectory, tmp_{t+1}[l] = sum_i tmp_t[i] * M[nt][i*32+l]
// 1 wave per trajectory; lanes (h,l) split i-range; 1-deep register prefetch
// ---------------------------------------------------------------------------
__global__ void scan_kernel(const float* __restrict__ M, const float* __restrict__ alpha,
                            const float* __restrict__ Omega, float* __restrict__ out, int n0) {
  __shared__ float stmp[R_];
  const int lane = threadIdx.x;        // 64
  const int l = lane & 31, h = lane >> 5;
  const float* Mn = M + (size_t)blockIdx.x * TSTEPS * MDIM;
  if (lane < R_) stmp[lane] = alpha[lane];
  __syncthreads();

  float cur[16], nxt[16];
#pragma unroll
  for (int m = 0; m < 16; ++m) cur[m] = Mn[(h * 16 + m) * 32 + l];

  for (int t = 0; t < TSTEPS; ++t) {
    if (t + 1 < TSTEPS) {
      const float* pn = Mn + (size_t)(t + 1) * MDIM;
#pragma unroll
      for (int m = 0; m < 16; ++m) nxt[m] = pn[(h * 16 + m) * 32 + l];
    }
    float part = 0.f;
#pragma unroll
    for (int m = 0; m < 16; ++m) part += stmp[h * 16 + m] * cur[m];
    part += __shfl_down(part, 32, 64);
    __syncthreads();
    if (lane < R_) stmp[lane] = part;
    __syncthreads();
#pragma unroll
    for (int m = 0; m < 16; ++m) cur[m] = nxt[m];
  }

  float v = (lane < R_) ? stmp[lane] * Omega[lane] : 0.f;
#pragma unroll
  for (int off = 16; off; off >>= 1) v += __shfl_down(v, off, 64);
  if (lane == 0) out[n0 + blockIdx.x] = v;
}

// ---------------------------------------------------------------------------
extern "C" void kernel_launch(void* const* d_in, const int* in_sizes, int n_in,
                              void* d_out, int out_size, void* d_ws, size_t ws_size,
                              hipStream_t stream) {
  const float* actions = (const float*)d_in[0];
  const float* obss    = (const float*)d_in[1];
  const float* Wa      = (const float*)d_in[2];
  const float* ba      = (const float*)d_in[3];
  const float* Wo      = (const float*)d_in[4];
  const float* bo      = (const float*)d_in[5];
  const float* alpha   = (const float*)d_in[6];
  const float* A       = (const float*)d_in[7];
  const float* Omega   = (const float*)d_in[8];
  float* out = (float*)d_out;

  char* ws = (char*)d_ws;
  float* Dbuf = (float*)ws;
  size_t off = (size_t)R_ * PDIM * DO_ * R_ * 4;       // 2,228,224
  float* Cbuf = (float*)(ws + off);
  off += (size_t)KPAD * MDIM * 4;                      // +1,310,720
  size_t fixed = off;

  // Pick largest trajectory chunk that fits the workspace.
  int NC = NTRAJ;
  while (NC > 1) {
    size_t need = fixed + (size_t)NC * TSTEPS * (KPAD + MDIM) * 4;
    if (need <= ws_size) break;
    NC >>= 1;
  }
  int NTc = NC * TSTEPS;
  float* Zt = (float*)(ws + fixed);
  float* M  = (float*)(ws + fixed + (size_t)NTc * KPAD * 4);

  hipLaunchKernelGGL(build_D, dim3((R_ * PDIM * DO_ * R_ + 255) / 256), dim3(256), 0, stream,
                     A, Wa, ba, Dbuf);
  hipLaunchKernelGGL(build_C, dim3((KPAD * MDIM + 255) / 256), dim3(256), 0, stream,
                     Dbuf, Wo, bo, Cbuf);

  for (int n0 = 0; n0 < NTRAJ; n0 += NC) {
    hipLaunchKernelGGL(build_Zt, dim3((NTc + 255) / 256), dim3(256), 0, stream,
                       actions, obss, Zt, n0, NTc);
    hipLaunchKernelGGL(gemm_M, dim3(NTc / BM, MDIM / BN), dim3(256), 0, stream,
                       Zt, Cbuf, M, NTc);
    hipLaunchKernelGGL(scan_kernel, dim3(NC), dim3(64), 0, stream,
                       M, alpha, Omega, out, n0);
  }
}

// Round 2
// 196.652 us; speedup vs baseline: 1.5571x; 1.5571x over previous
//
#include <hip/hip_runtime.h>

typedef __bf16 bf16_t;
typedef bf16_t bf16x8 __attribute__((ext_vector_type(8)));
typedef float f32x4 __attribute__((ext_vector_type(4)));

#define R_ 32
#define DA_ 32
#define DO_ 32
#define NTRAJ 256
#define TSTEPS 128
#define PDIM 17
#define KTRUE 289
#define KSEG 320          // padded per-segment K
#define KZ 640            // Zcat cols: [Zh(320) | Zl(320)]
#define KBC 960           // Ct cols:   [Ch(320) | Ch(320) | Cl(320)]
#define MDIM 1024

// ---------------------------------------------------------------------------
// D[i,p,k,l] = sum_j Wa'[p,j] * A[i,j,k,l]   (Wa' row 16 = ba)  fp32
// ---------------------------------------------------------------------------
__global__ void build_D(const float* __restrict__ A, const float* __restrict__ Wa,
                        const float* __restrict__ ba, float* __restrict__ D) {
  int id = blockIdx.x * blockDim.x + threadIdx.x;
  if (id >= R_ * PDIM * DO_ * R_) return;
  int l = id & 31;
  int k = (id >> 5) & 31;
  int p = (id >> 10) % PDIM;
  int i = id / (PDIM * 1024);
  const float* Ab = A + (size_t)i * 32768 + k * 32 + l;
  float s = 0.f;
  if (p < 16) {
    const float* w = Wa + p * DA_;
#pragma unroll 8
    for (int j = 0; j < DA_; ++j) s += w[j] * Ab[j * 1024];
  } else {
#pragma unroll 8
    for (int j = 0; j < DA_; ++j) s += ba[j] * Ab[j * 1024];
  }
  D[id] = s;  // flat = i*17408 + p*1024 + k*32 + l
}

// ---------------------------------------------------------------------------
// Ct[il][0..319]=Ch, [320..639]=Ch, [640..959]=Cl  (row-major, K-contig)
// C[pq,il] = sum_k Wo'[q,k] * D[i,p,k,l]
// ---------------------------------------------------------------------------
__global__ void build_C(const float* __restrict__ D, const float* __restrict__ Wo,
                        const float* __restrict__ bo, bf16_t* __restrict__ Ct) {
  int id = blockIdx.x * blockDim.x + threadIdx.x;
  if (id >= KSEG * MDIM) return;
  int pq = id % KSEG;
  int il = id / KSEG;
  float s = 0.f;
  if (pq < KTRUE) {
    int p = pq / PDIM, q = pq % PDIM;
    int i = il >> 5, l = il & 31;
    const float* Db = D + (size_t)(i * PDIM + p) * 1024 + l;  // k stride 32
    if (q < 16) {
      const float* w = Wo + q * DO_;
#pragma unroll 8
      for (int k = 0; k < DO_; ++k) s += w[k] * Db[k * 32];
    } else {
#pragma unroll 8
      for (int k = 0; k < DO_; ++k) s += bo[k] * Db[k * 32];
    }
  }
  bf16_t h = (bf16_t)s;
  bf16_t lo = (bf16_t)(s - (float)h);
  size_t base = (size_t)il * KBC;
  Ct[base + pq] = h;
  Ct[base + KSEG + pq] = h;
  Ct[base + 2 * KSEG + pq] = lo;
}

// ---------------------------------------------------------------------------
// Zcat[nt][KZ] bf16 row-major: cols [0,320)=hi(Z), [320,640)=lo(Z)
// Z[nt,pq] = a'[p]*o'[q];  pads (pq in [289,320)) zero.
// ---------------------------------------------------------------------------
__global__ void build_Zt(const float* __restrict__ actions, const float* __restrict__ obss,
                         unsigned* __restrict__ Z, int n0) {
  __shared__ float sav[8][PDIM];
  __shared__ float sov[8][PDIM];
  const int r = threadIdx.x >> 5;
  const int c = threadIdx.x & 31;
  const int nt = blockIdx.x * 8 + r;
  const size_t gnt = (size_t)n0 * TSTEPS + nt;
  if (c < PDIM) {
    sav[r][c] = (c < 16) ? actions[gnt * 16 + c] : 1.f;
    sov[r][c] = (c < 16) ? obss[gnt * 16 + c] : 1.f;
  }
  __syncthreads();
  unsigned* zr = Z + (size_t)nt * (KZ / 2);
#pragma unroll
  for (int u = 0; u < 10; ++u) {
    int col = u * 32 + c;        // uint col (2 bf16)
    int k0 = col * 2;
    bool hiplane = (k0 < KSEG);
    int kk = hiplane ? k0 : k0 - KSEG;
    unsigned short h0, h1;
    {
      float z = 0.f;
      if (kk < KTRUE) z = sav[r][kk / PDIM] * sov[r][kk % PDIM];
      bf16_t zh = (bf16_t)z;
      bf16_t zl = (bf16_t)(z - (float)zh);
      h0 = __builtin_bit_cast(unsigned short, hiplane ? zh : zl);
    }
    {
      int k1 = kk + 1;
      float z = 0.f;
      if (k1 < KTRUE) z = sav[r][k1 / PDIM] * sov[r][k1 % PDIM];
      bf16_t zh = (bf16_t)z;
      bf16_t zl = (bf16_t)(z - (float)zh);
      h1 = __builtin_bit_cast(unsigned short, hiplane ? zh : zl);
    }
    zr[col] = (unsigned)h0 | ((unsigned)h1 << 16);
  }
}

// ---------------------------------------------------------------------------
// M[nt,il] (fp32) = Zh*Ch + Zl*Ch + Zh*Cl via one K'=960 bf16 MFMA GEMM.
// 128x128 tile, 4 waves (2x2), BK=64, global_load_lds w/ pre-swizzled source,
// XOR-swizzled ds_read_b128, mfma_f32_16x16x32_bf16.
// ---------------------------------------------------------------------------
__device__ __forceinline__ void gload16(const void* g, void* lds) {
  __builtin_amdgcn_global_load_lds(
      (const __attribute__((address_space(1))) void*)g,
      (__attribute__((address_space(3))) void*)lds, 16, 0, 0);
}

__global__ __launch_bounds__(256) void gemm_M(const bf16_t* __restrict__ Z,
                                              const bf16_t* __restrict__ Ct,
                                              float* __restrict__ Mout, int NTc) {
  __shared__ char lds[32768];
  char* As = lds;            // [128 rows][64 k] bf16, 16B units XOR (row&7)
  char* Bs = lds + 16384;    // [128 n  ][64 k] bf16, same swizzle

  const int nbx = NTc >> 7;
  const int cpx = nbx;                 // nwg/8 = nbx
  const int bid = blockIdx.x;
  const int wg = (bid & 7) * cpx + (bid >> 3);   // bijective XCD swizzle
  const int bm = (wg >> 3) << 7;
  const int bn = (wg & 7) << 7;

  const int tid = threadIdx.x;
  const int w = tid >> 6, l = tid & 63;
  const int wr = w >> 1, wc = w & 1;
  const int lrow = l & 15, lk = l >> 4;      // frag row/col, k-group
  const int srow = l >> 3;                   // staging row-in-chunk (0..7)
  const int jsrc = (l & 7) ^ srow;           // pre-swizzled source 16B-unit

  f32x4 acc[4][4] = {};

  for (int kt = 0; kt < 15; ++kt) {
    const int kb = kt << 6;                  // k' tile base (0..896)
    const int ka = (kb < 2 * KSEG) ? kb : kb - 2 * KSEG;  // Zcat col base
#pragma unroll
    for (int c2 = 0; c2 < 4; ++c2) {
      const int chunk = w * 4 + c2;          // 0..15, 1KB each
      const int row = chunk * 8 + srow;      // 0..127
      gload16(Z + ((size_t)(bm + row) * KZ + ka + jsrc * 8), As + chunk * 1024);
      gload16(Ct + ((size_t)(bn + row) * KBC + kb + jsrc * 8), Bs + chunk * 1024);
    }
    __syncthreads();
#pragma unroll
    for (int ksub = 0; ksub < 2; ++ksub) {
      const int j = ksub * 4 + lk;
      bf16x8 af[4], bfr[4];
#pragma unroll
      for (int m = 0; m < 4; ++m) {
        const int row = wr * 64 + m * 16 + lrow;
        const int u = j ^ (row & 7);
        af[m] = *(const bf16x8*)(As + row * 128 + u * 16);
      }
#pragma unroll
      for (int n = 0; n < 4; ++n) {
        const int row = wc * 64 + n * 16 + lrow;
        const int u = j ^ (row & 7);
        bfr[n] = *(const bf16x8*)(Bs + row * 128 + u * 16);
      }
#pragma unroll
      for (int m = 0; m < 4; ++m)
#pragma unroll
        for (int n = 0; n < 4; ++n)
          acc[m][n] = __builtin_amdgcn_mfma_f32_16x16x32_bf16(af[m], bfr[n], acc[m][n], 0, 0, 0);
    }
    __syncthreads();
  }
  // epilogue: C/D layout col=lane&15, row=(lane>>4)*4+reg  (m89-verified)
#pragma unroll
  for (int m = 0; m < 4; ++m) {
    const int row0 = bm + wr * 64 + m * 16 + lk * 4;
#pragma unroll
    for (int n = 0; n < 4; ++n) {
      const int col = bn + wc * 64 + n * 16 + lrow;
#pragma unroll
      for (int r2 = 0; r2 < 4; ++r2)
        Mout[(size_t)(row0 + r2) * MDIM + col] = acc[m][n][r2];
    }
  }
}

// ---------------------------------------------------------------------------
// Scan: tmp_{t+1}[l] = sum_i tmp_t[i]*M_t[i,l]; 1 wave/traj, lane=(ig,lg)
// owns 4x4 block; depth-8 register prefetch; shfl-only reduce/broadcast.
// ---------------------------------------------------------------------------
__global__ void scan_kernel(const float* __restrict__ M, const float* __restrict__ alpha,
                            const float* __restrict__ Omega, float* __restrict__ out, int n0) {
  const int l = threadIdx.x;
  const int ig = l >> 3, lg = l & 7;
  const float* Mn = M + (size_t)blockIdx.x * TSTEPS * MDIM + ig * 128 + lg * 4;
  float s0 = alpha[ig * 4 + 0], s1 = alpha[ig * 4 + 1];
  float s2 = alpha[ig * 4 + 2], s3 = alpha[ig * 4 + 3];
  f32x4 b0[4], b1[4], b2[4], b3[4], b4[4], b5[4], b6[4], b7[4];

#define LOADB(B, t)                                     \
  { const float* p_ = Mn + (size_t)(t) * MDIM;          \
    B[0] = *(const f32x4*)(p_);                         \
    B[1] = *(const f32x4*)(p_ + 32);                    \
    B[2] = *(const f32x4*)(p_ + 64);                    \
    B[3] = *(const f32x4*)(p_ + 96); }

  LOADB(b0, 0) LOADB(b1, 1) LOADB(b2, 2) LOADB(b3, 3)
  LOADB(b4, 4) LOADB(b5, 5) LOADB(b6, 6) LOADB(b7, 7)

#define STEPB(B, t)                                                    \
  { f32x4 part = B[0] * s0;                                            \
    part += B[1] * s1; part += B[2] * s2; part += B[3] * s3;           \
    if ((t) + 8 < TSTEPS) LOADB(B, (t) + 8)                            \
    float p0 = part[0], p1 = part[1], p2 = part[2], p3 = part[3];      \
    p0 += __shfl_down(p0, 8, 64);  p1 += __shfl_down(p1, 8, 64);       \
    p2 += __shfl_down(p2, 8, 64);  p3 += __shfl_down(p3, 8, 64);       \
    p0 += __shfl_down(p0, 16, 64); p1 += __shfl_down(p1, 16, 64);      \
    p2 += __shfl_down(p2, 16, 64); p3 += __shfl_down(p3, 16, 64);      \
    p0 += __shfl_down(p0, 32, 64); p1 += __shfl_down(p1, 32, 64);      \
    p2 += __shfl_down(p2, 32, 64); p3 += __shfl_down(p3, 32, 64);      \
    s0 = __shfl(p0, ig, 64); s1 = __shfl(p1, ig, 64);                  \
    s2 = __shfl(p2, ig, 64); s3 = __shfl(p3, ig, 64); }

  for (int tt = 0; tt < TSTEPS / 8; ++tt) {
    const int t = tt * 8;
    STEPB(b0, t + 0) STEPB(b1, t + 1) STEPB(b2, t + 2) STEPB(b3, t + 3)
    STEPB(b4, t + 4) STEPB(b5, t + 5) STEPB(b6, t + 6) STEPB(b7, t + 7)
  }

  float v = 0.f;
  if (lg == 0)
    v = s0 * Omega[ig * 4 + 0] + s1 * Omega[ig * 4 + 1] +
        s2 * Omega[ig * 4 + 2] + s3 * Omega[ig * 4 + 3];
  v += __shfl_down(v, 32, 64);
  v += __shfl_down(v, 16, 64);
  v += __shfl_down(v, 8, 64);
  if (l == 0) out[n0 + blockIdx.x] = v;
}

// ---------------------------------------------------------------------------
extern "C" void kernel_launch(void* const* d_in, const int* in_sizes, int n_in,
                              void* d_out, int out_size, void* d_ws, size_t ws_size,
                              hipStream_t stream) {
  const float* actions = (const float*)d_in[0];
  const float* obss    = (const float*)d_in[1];
  const float* Wa      = (const float*)d_in[2];
  const float* ba      = (const float*)d_in[3];
  const float* Wo      = (const float*)d_in[4];
  const float* bo      = (const float*)d_in[5];
  const float* alpha   = (const float*)d_in[6];
  const float* A       = (const float*)d_in[7];
  const float* Omega   = (const float*)d_in[8];
  float* out = (float*)d_out;

  char* ws = (char*)d_ws;
  size_t fixed = ((size_t)KBC * MDIM * 2 + 255) & ~(size_t)255;  // Ct ~1.97MB

  int NC = NTRAJ;
  while (NC > 8) {
    size_t need = fixed + (size_t)NC * TSTEPS * ((size_t)KZ * 2 + MDIM * 4);
    if (need <= ws_size) break;
    NC >>= 1;
  }
  const int NTc = NC * TSTEPS;
  bf16_t*  Ct = (bf16_t*)ws;
  unsigned* Zu = (unsigned*)(ws + fixed);
  float*   M  = (float*)(ws + fixed + (size_t)NTc * KZ * 2);
  float*   Dbuf = (float*)(ws + fixed);  // overlay: consumed before Z/M written

  hipLaunchKernelGGL(build_D, dim3((R_ * PDIM * DO_ * R_ + 255) / 256), dim3(256), 0, stream,
                     A, Wa, ba, Dbuf);
  hipLaunchKernelGGL(build_C, dim3((KSEG * MDIM + 255) / 256), dim3(256), 0, stream,
                     Dbuf, Wo, bo, Ct);

  for (int n0 = 0; n0 < NTRAJ; n0 += NC) {
    hipLaunchKernelGGL(build_Zt, dim3(NTc / 8), dim3(256), 0, stream,
                       actions, obss, Zu, n0);
    hipLaunchKernelGGL(gemm_M, dim3((NTc / 128) * 8), dim3(256), 0, stream,
                       (const bf16_t*)Zu, Ct, M, NTc);
    hipLaunchKernelGGL(scan_kernel, dim3(NC), dim3(64), 0, stream,
                       M, alpha, Omega, out, n0);
  }
}

// Round 5
// 150.227 us; speedup vs baseline: 2.0383x; 1.3090x over previous
//
#include <hip/hip_runtime.h>

typedef __bf16 bf16_t;
typedef bf16_t bf16x8 __attribute__((ext_vector_type(8)));
typedef float f32x4 __attribute__((ext_vector_type(4)));
typedef _Float16 f16x4 __attribute__((ext_vector_type(4)));

#define R_ 32
#define DA_ 32
#define DO_ 32
#define NTRAJ 256
#define TSTEPS 128
#define PDIM 17
#define KTRUE 289
#define KSEG 320          // padded per-segment K
#define KZ 640            // Zcat cols: [Zh(320) | Zl(320)]
#define KBC 960           // Ct cols:   [Ch(320) | Ch(320) | Cl(320)]
#define NKT 15            // 960/64 K-tiles
#define MDIM 1024

#define SBAR() __builtin_amdgcn_s_barrier()
#define SCHED0() __builtin_amdgcn_sched_barrier(0)
#define PRIO(x) __builtin_amdgcn_s_setprio(x)

// ---------------------------------------------------------------------------
// D[i,p,k,l] = sum_j Wa'[p,j] * A[i,j,k,l]   (Wa' row 16 = ba)  fp32
// ---------------------------------------------------------------------------
__global__ void build_D(const float* __restrict__ A, const float* __restrict__ Wa,
                        const float* __restrict__ ba, float* __restrict__ D) {
  int id = blockIdx.x * blockDim.x + threadIdx.x;
  if (id >= R_ * PDIM * DO_ * R_) return;
  int l = id & 31;
  int k = (id >> 5) & 31;
  int p = (id >> 10) % PDIM;
  int i = id / (PDIM * 1024);
  const float* Ab = A + (size_t)i * 32768 + k * 32 + l;
  float s = 0.f;
  if (p < 16) {
    const float* w = Wa + p * DA_;
#pragma unroll 8
    for (int j = 0; j < DA_; ++j) s += w[j] * Ab[j * 1024];
  } else {
#pragma unroll 8
    for (int j = 0; j < DA_; ++j) s += ba[j] * Ab[j * 1024];
  }
  D[id] = s;  // flat = i*17408 + p*1024 + k*32 + l
}

// ---------------------------------------------------------------------------
// Ct[il][0..319]=Ch, [320..639]=Ch, [640..959]=Cl  (row-major, K-contig)
// ---------------------------------------------------------------------------
__global__ void build_C(const float* __restrict__ D, const float* __restrict__ Wo,
                        const float* __restrict__ bo, bf16_t* __restrict__ Ct) {
  int id = blockIdx.x * blockDim.x + threadIdx.x;
  if (id >= KSEG * MDIM) return;
  int pq = id % KSEG;
  int il = id / KSEG;
  float s = 0.f;
  if (pq < KTRUE) {
    int p = pq / PDIM, q = pq % PDIM;
    int i = il >> 5, l = il & 31;
    const float* Db = D + (size_t)(i * PDIM + p) * 1024 + l;  // k stride 32
    if (q < 16) {
      const float* w = Wo + q * DO_;
#pragma unroll 8
      for (int k = 0; k < DO_; ++k) s += w[k] * Db[k * 32];
    } else {
#pragma unroll 8
      for (int k = 0; k < DO_; ++k) s += bo[k] * Db[k * 32];
    }
  }
  bf16_t h = (bf16_t)s;
  bf16_t lo = (bf16_t)(s - (float)h);
  size_t base = (size_t)il * KBC;
  Ct[base + pq] = h;
  Ct[base + KSEG + pq] = h;
  Ct[base + 2 * KSEG + pq] = lo;
}

// ---------------------------------------------------------------------------
// Zcat[nt][KZ] bf16 row-major: cols [0,320)=hi(Z), [320,640)=lo(Z)
// ---------------------------------------------------------------------------
__global__ void build_Zt(const float* __restrict__ actions, const float* __restrict__ obss,
                         unsigned* __restrict__ Z, int n0) {
  __shared__ float sav[8][PDIM];
  __shared__ float sov[8][PDIM];
  const int r = threadIdx.x >> 5;
  const int c = threadIdx.x & 31;
  const int nt = blockIdx.x * 8 + r;
  const size_t gnt = (size_t)n0 * TSTEPS + nt;
  if (c < PDIM) {
    sav[r][c] = (c < 16) ? actions[gnt * 16 + c] : 1.f;
    sov[r][c] = (c < 16) ? obss[gnt * 16 + c] : 1.f;
  }
  __syncthreads();
  unsigned* zr = Z + (size_t)nt * (KZ / 2);
#pragma unroll
  for (int u = 0; u < 10; ++u) {
    int col = u * 32 + c;
    int k0 = col * 2;
    bool hiplane = (k0 < KSEG);
    int kk = hiplane ? k0 : k0 - KSEG;
    unsigned short h0, h1;
    {
      float z = 0.f;
      if (kk < KTRUE) z = sav[r][kk / PDIM] * sov[r][kk % PDIM];
      bf16_t zh = (bf16_t)z;
      bf16_t zl = (bf16_t)(z - (float)zh);
      h0 = __builtin_bit_cast(unsigned short, hiplane ? zh : zl);
    }
    {
      int k1 = kk + 1;
      float z = 0.f;
      if (k1 < KTRUE) z = sav[r][k1 / PDIM] * sov[r][k1 % PDIM];
      bf16_t zh = (bf16_t)z;
      bf16_t zl = (bf16_t)(z - (float)zh);
      h1 = __builtin_bit_cast(unsigned short, hiplane ? zh : zl);
    }
    zr[col] = (unsigned)h0 | ((unsigned)h1 << 16);
  }
}

// ---------------------------------------------------------------------------
// 256x256 8-phase MFMA GEMM: M[nt,il](fp16) = Zcat x Ct^T over K'=960.
// 8 waves (2Mx4N), BK=64, 128KB STATIC LDS dbuf, counted vmcnt(8),
// XOR-swizzled LDS. Tile kt+2 staged into buffer p (region retirement).
// ---------------------------------------------------------------------------
__device__ __forceinline__ void gload16(const void* g, void* lds_) {
  __builtin_amdgcn_global_load_lds(
      (const __attribute__((address_space(1))) void*)g,
      (__attribute__((address_space(3))) void*)lds_, 16, 0, 0);
}

__global__ __launch_bounds__(512, 2) void gemm_M(const bf16_t* __restrict__ Z,
                                                 const bf16_t* __restrict__ Ct,
                                                 _Float16* __restrict__ Mout, int NTc) {
  __shared__ char lds[131072];
  const int nbm = NTc >> 8;
  const int nwg = nbm * 4;
  const int cpx = nwg >> 3;
  const int bid = blockIdx.x;
  const int wg = (bid & 7) * cpx + (bid >> 3);   // bijective XCD swizzle (nwg%8==0)
  const int bm = (wg >> 2) << 8;
  const int bn = (wg & 3) << 8;

  const int tid = threadIdx.x;
  const int w = tid >> 6, lane = tid & 63;
  const int wr = w >> 2, wc = w & 3;             // 2x4 wave grid
  const int lrow = lane & 15, lk = lane >> 4;
  const int u0 = lk ^ (lrow & 7);                // 16B-unit for ksub 0
  const int u1 = (lk + 4) ^ (lrow & 7);          // ksub 1

  // staging geometry: chunk = 1KB = 8 rows; lane writes row srow, unit lane&7
  const int srow = lane >> 3;
  const int jsrc = (lane & 7) ^ srow;            // pre-swizzled global 16B unit
  const char* Zb = (const char*)Z + (size_t)(bm + srow) * (KZ * 2) + jsrc * 16;
  const char* Cb = (const char*)Ct + (size_t)(bn + srow) * (KBC * 2) + jsrc * 16;

  // A stage: sel 0 -> chunks {0-7,16-23} (rows 0-63,128-191; retired after P1)
  //          sel 1 -> chunks {8-15,24-31} (rows 64-127,192-255; after P3)
  auto stageA = [&](char* Ab, int sel, int kt) {
    const size_t ka = (size_t)((kt < 10) ? kt : kt - 10) * 128;
#pragma unroll
    for (int r = 0; r < 2; ++r) {
      int e = w * 2 + r;
      int c = sel ? (e + 8 + ((e >= 8) ? 8 : 0)) : (e + ((e >= 8) ? 8 : 0));
      gload16(Zb + (size_t)c * 8 * (KZ * 2) + ka, Ab + c * 1024);
    }
  };
  auto stageB = [&](char* Bb, int half, int kt) {
    const size_t kb = (size_t)kt * 128;
#pragma unroll
    for (int r = 0; r < 2; ++r) {
      int c = w * 2 + r;
      gload16(Cb + (size_t)(half * 128 + c * 8) * (KBC * 2) + kb,
              Bb + half * 16384 + c * 1024);
    }
  };

  f32x4 acc[8][4] = {};
  bf16x8 af[4][2], bfr[4][2];

  // prologue: stage tiles 0 and 1 (8 gloads each, FIFO order)
  stageA(lds, 0, 0); stageA(lds, 1, 0);
  stageB(lds + 32768, 0, 0); stageB(lds + 32768, 1, 0);
  stageA(lds + 65536, 0, 1); stageA(lds + 65536, 1, 1);
  stageB(lds + 98304, 0, 1); stageB(lds + 98304, 1, 1);
  asm volatile("s_waitcnt vmcnt(8)" ::: "memory"); SCHED0();
  SBAR(); SCHED0();

  for (int kt = 0; kt < NKT; ++kt) {
    const int p = kt & 1;
    char* Ap = lds + (p << 16);
    char* Bp = Ap + 32768;
    const bool doStage = (kt + 2 < NKT);

    // ---- P1: ds_read A-quarter0 (mf0-3) + B-all; lgkm BEFORE barrier ----
#pragma unroll
    for (int mf = 0; mf < 4; ++mf) {
      const char* rp = Ap + (wr * 128 + mf * 16 + lrow) * 128;
      af[mf][0] = *(const bf16x8*)(rp + u0 * 16);
      af[mf][1] = *(const bf16x8*)(rp + u1 * 16);
    }
#pragma unroll
    for (int nf = 0; nf < 4; ++nf) {
      const char* cp = Bp + (wc * 64 + nf * 16 + lrow) * 128;
      bfr[nf][0] = *(const bf16x8*)(cp + u0 * 16);
      bfr[nf][1] = *(const bf16x8*)(cp + u1 * 16);
    }
    SCHED0();
    asm volatile("s_waitcnt lgkmcnt(0)" ::: "memory"); SCHED0();
    SBAR(); SCHED0();
    PRIO(1);
#pragma unroll
    for (int ks = 0; ks < 2; ++ks)
#pragma unroll
      for (int mf = 0; mf < 4; ++mf)
#pragma unroll
        for (int nf = 0; nf < 2; ++nf)
          acc[mf][nf] = __builtin_amdgcn_mfma_f32_16x16x32_bf16(af[mf][ks], bfr[nf][ks], acc[mf][nf], 0, 0, 0);
    PRIO(0);
    SCHED0(); SBAR(); SCHED0();

    // ---- P2: stage tile kt+2 A-sel0 + B-both into buffer p (retired) ----
    if (doStage) { stageA(Ap, 0, kt + 2); stageB(Bp, 0, kt + 2); stageB(Bp, 1, kt + 2); }
    PRIO(1);
#pragma unroll
    for (int ks = 0; ks < 2; ++ks)
#pragma unroll
      for (int mf = 0; mf < 4; ++mf)
#pragma unroll
        for (int nf = 2; nf < 4; ++nf)
          acc[mf][nf] = __builtin_amdgcn_mfma_f32_16x16x32_bf16(af[mf][ks], bfr[nf][ks], acc[mf][nf], 0, 0, 0);
    PRIO(0);
    SCHED0(); SBAR(); SCHED0();

    // ---- P3: ds_read A-quarter1 (mf4-7); lgkm BEFORE barrier ----
#pragma unroll
    for (int mf = 0; mf < 4; ++mf) {
      const char* rp = Ap + (wr * 128 + (mf + 4) * 16 + lrow) * 128;
      af[mf][0] = *(const bf16x8*)(rp + u0 * 16);
      af[mf][1] = *(const bf16x8*)(rp + u1 * 16);
    }
    SCHED0();
    asm volatile("s_waitcnt lgkmcnt(0)" ::: "memory"); SCHED0();
    SBAR(); SCHED0();
    PRIO(1);
#pragma unroll
    for (int ks = 0; ks < 2; ++ks)
#pragma unroll
      for (int mf = 0; mf < 4; ++mf)
#pragma unroll
        for (int nf = 0; nf < 2; ++nf)
          acc[mf + 4][nf] = __builtin_amdgcn_mfma_f32_16x16x32_bf16(af[mf][ks], bfr[nf][ks], acc[mf + 4][nf], 0, 0, 0);
    PRIO(0);
    SCHED0(); SBAR(); SCHED0();

    // ---- P4: stage tile kt+2 A-sel1 into buffer p; counted vmcnt gate ----
    if (doStage) stageA(Ap, 1, kt + 2);
    PRIO(1);
#pragma unroll
    for (int ks = 0; ks < 2; ++ks)
#pragma unroll
      for (int mf = 0; mf < 4; ++mf)
#pragma unroll
        for (int nf = 2; nf < 4; ++nf)
          acc[mf + 4][nf] = __builtin_amdgcn_mfma_f32_16x16x32_bf16(af[mf][ks], bfr[nf][ks], acc[mf + 4][nf], 0, 0, 0);
    PRIO(0);
    if (kt <= NKT - 3) {
      asm volatile("s_waitcnt vmcnt(8)" ::: "memory");
    } else if (kt == NKT - 2) {
      asm volatile("s_waitcnt vmcnt(0)" ::: "memory");
    }
    SCHED0(); SBAR(); SCHED0();
  }

  // epilogue: C/D layout col=lane&15, row=(lane>>4)*4+reg (m89-verified, R2-passed)
#pragma unroll
  for (int mf = 0; mf < 8; ++mf) {
    const int row0 = bm + wr * 128 + mf * 16 + lk * 4;
#pragma unroll
    for (int nf = 0; nf < 4; ++nf) {
      const int col = bn + wc * 64 + nf * 16 + lrow;
#pragma unroll
      for (int r2 = 0; r2 < 4; ++r2)
        Mout[(size_t)(row0 + r2) * MDIM + col] = (_Float16)acc[mf][nf][r2];
    }
  }
}

// ---------------------------------------------------------------------------
// Scan: tmp_{t+1}[l] = sum_i tmp_t[i]*M_t[i,l]; 1 wave/traj; M is fp16.
// ---------------------------------------------------------------------------
__global__ void scan_kernel(const _Float16* __restrict__ M, const float* __restrict__ alpha,
                            const float* __restrict__ Omega, float* __restrict__ out, int n0) {
  const int l = threadIdx.x;
  const int ig = l >> 3, lg = l & 7;
  const char* Mn = (const char*)M + (size_t)blockIdx.x * TSTEPS * 2048 + (size_t)(ig * 128 + lg * 4) * 2;
  float s0 = alpha[ig * 4 + 0], s1 = alpha[ig * 4 + 1];
  float s2 = alpha[ig * 4 + 2], s3 = alpha[ig * 4 + 3];
  f16x4 b0[4], b1[4], b2[4], b3[4], b4[4], b5[4], b6[4], b7[4];

#define LOADB(B, t)                                     \
  { const char* p_ = Mn + (size_t)(t) * 2048;           \
    B[0] = *(const f16x4*)(p_);                         \
    B[1] = *(const f16x4*)(p_ + 64);                    \
    B[2] = *(const f16x4*)(p_ + 128);                   \
    B[3] = *(const f16x4*)(p_ + 192); }

  LOADB(b0, 0) LOADB(b1, 1) LOADB(b2, 2) LOADB(b3, 3)
  LOADB(b4, 4) LOADB(b5, 5) LOADB(b6, 6) LOADB(b7, 7)

#define STEPB(B, t)                                                    \
  { f32x4 part = __builtin_convertvector(B[0], f32x4) * s0;            \
    part += __builtin_convertvector(B[1], f32x4) * s1;                 \
    part += __builtin_convertvector(B[2], f32x4) * s2;                 \
    part += __builtin_convertvector(B[3], f32x4) * s3;                 \
    if ((t) + 8 < TSTEPS) LOADB(B, (t) + 8)                            \
    float p0 = part[0], p1 = part[1], p2 = part[2], p3 = part[3];      \
    p0 += __shfl_down(p0, 8, 64);  p1 += __shfl_down(p1, 8, 64);       \
    p2 += __shfl_down(p2, 8, 64);  p3 += __shfl_down(p3, 8, 64);       \
    p0 += __shfl_down(p0, 16, 64); p1 += __shfl_down(p1, 16, 64);      \
    p2 += __shfl_down(p2, 16, 64); p3 += __shfl_down(p3, 16, 64);      \
    p0 += __shfl_down(p0, 32, 64); p1 += __shfl_down(p1, 32, 64);      \
    p2 += __shfl_down(p2, 32, 64); p3 += __shfl_down(p3, 32, 64);      \
    s0 = __shfl(p0, ig, 64); s1 = __shfl(p1, ig, 64);                  \
    s2 = __shfl(p2, ig, 64); s3 = __shfl(p3, ig, 64); }

  for (int tt = 0; tt < TSTEPS / 8; ++tt) {
    const int t = tt * 8;
    STEPB(b0, t + 0) STEPB(b1, t + 1) STEPB(b2, t + 2) STEPB(b3, t + 3)
    STEPB(b4, t + 4) STEPB(b5, t + 5) STEPB(b6, t + 6) STEPB(b7, t + 7)
  }

  float v = 0.f;
  if (lg == 0)
    v = s0 * Omega[ig * 4 + 0] + s1 * Omega[ig * 4 + 1] +
        s2 * Omega[ig * 4 + 2] + s3 * Omega[ig * 4 + 3];
  v += __shfl_down(v, 32, 64);
  v += __shfl_down(v, 16, 64);
  v += __shfl_down(v, 8, 64);
  if (l == 0) out[n0 + blockIdx.x] = v;
}

// ---------------------------------------------------------------------------
extern "C" void kernel_launch(void* const* d_in, const int* in_sizes, int n_in,
                              void* d_out, int out_size, void* d_ws, size_t ws_size,
                              hipStream_t stream) {
  const float* actions = (const float*)d_in[0];
  const float* obss    = (const float*)d_in[1];
  const float* Wa      = (const float*)d_in[2];
  const float* ba      = (const float*)d_in[3];
  const float* Wo      = (const float*)d_in[4];
  const float* bo      = (const float*)d_in[5];
  const float* alpha   = (const float*)d_in[6];
  const float* A       = (const float*)d_in[7];
  const float* Omega   = (const float*)d_in[8];
  float* out = (float*)d_out;

  char* ws = (char*)d_ws;
  size_t fixed = ((size_t)KBC * MDIM * 2 + 255) & ~(size_t)255;  // Ct ~1.97MB

  int NC = NTRAJ;
  while (NC > 8) {
    size_t need = fixed + (size_t)NC * TSTEPS * ((size_t)KZ * 2 + MDIM * 2);
    if (need <= ws_size) break;
    NC >>= 1;
  }
  const int NTc = NC * TSTEPS;
  bf16_t*   Ct = (bf16_t*)ws;
  unsigned* Zu = (unsigned*)(ws + fixed);
  _Float16* M  = (_Float16*)(ws + fixed + (size_t)NTc * KZ * 2);
  float*    Dbuf = (float*)(ws + fixed);  // overlay: consumed before Z written

  hipLaunchKernelGGL(build_D, dim3((R_ * PDIM * DO_ * R_ + 255) / 256), dim3(256), 0, stream,
                     A, Wa, ba, Dbuf);
  hipLaunchKernelGGL(build_C, dim3((KSEG * MDIM + 255) / 256), dim3(256), 0, stream,
                     Dbuf, Wo, bo, Ct);

  for (int n0 = 0; n0 < NTRAJ; n0 += NC) {
    hipLaunchKernelGGL(build_Zt, dim3(NTc / 8), dim3(256), 0, stream,
                       actions, obss, Zu, n0);
    hipLaunchKernelGGL(gemm_M, dim3((NTc >> 8) * 4), dim3(512), 0, stream,
                       (const bf16_t*)Zu, Ct, M, NTc);
    hipLaunchKernelGGL(scan_kernel, dim3(NC), dim3(64), 0, stream,
                       M, alpha, Omega, out, n0);
  }
}

// Round 6
// 104.526 us; speedup vs baseline: 2.9295x; 1.4372x over previous
//
#include <hip/hip_runtime.h>

typedef _Float16 f16_t;
typedef f16_t f16x8 __attribute__((ext_vector_type(8)));
typedef f16_t f16x4 __attribute__((ext_vector_type(4)));
typedef float f32x4 __attribute__((ext_vector_type(4)));

#define R_ 32
#define NTRAJ 256
#define TSTEPS 128
#define PDIM 17
#define KTRUE 289
#define KSEG 320          // padded K (5 x 64)
#define NKT 5             // K-tiles
#define MDIM 1024

#define SBAR() __builtin_amdgcn_s_barrier()
#define SCHED0() __builtin_amdgcn_sched_barrier(0)
#define PRIO(x) __builtin_amdgcn_s_setprio(x)

// ---------------------------------------------------------------------------
// Fused: Ct[il][pq] (fp16, row-major K-contig) from A, Wa', Wo'.
// Grid 128 = (i in 0..31) x (l-group of 8). D-slice kept in regs then LDS.
// ---------------------------------------------------------------------------
__global__ __launch_bounds__(256) void build_Ct(const float* __restrict__ A,
                                                const float* __restrict__ Wa,
                                                const float* __restrict__ ba,
                                                const float* __restrict__ Wo,
                                                const float* __restrict__ bo,
                                                f16_t* __restrict__ Ct) {
  __shared__ float Dls[PDIM][32][8];   // [p][k][l']
  __shared__ float Was[PDIM][33];
  __shared__ float Wos[PDIM][33];
  const int tid = threadIdx.x;
  const int i = blockIdx.x >> 2;
  const int l0 = (blockIdx.x & 3) * 8;

  for (int e = tid; e < PDIM * 32; e += 256) {
    int p = e >> 5, j = e & 31;
    Was[p][j] = (p < 16) ? Wa[p * 32 + j] : ba[j];
    Wos[p][j] = (p < 16) ? Wo[p * 32 + j] : bo[j];
  }
  const int k = tid >> 3, lp = tid & 7;
  float Dreg[PDIM] = {};
  const float* Abase = A + (size_t)i * 32768 + k * 32 + l0 + lp;
  __syncthreads();
#pragma unroll
  for (int j = 0; j < 32; ++j) {
    float a = Abase[(size_t)j * 1024];
#pragma unroll
    for (int p = 0; p < PDIM; ++p) Dreg[p] += Was[p][j] * a;
  }
#pragma unroll
  for (int p = 0; p < PDIM; ++p) Dls[p][k][lp] = Dreg[p];
  __syncthreads();

  for (int v = tid; v < KTRUE * 8; v += 256) {
    int pq = v >> 3, l = v & 7;
    int p = pq / PDIM, q = pq % PDIM;
    float s = 0.f;
#pragma unroll
    for (int kk = 0; kk < 32; ++kk) s += Wos[q][kk] * Dls[p][kk][l];
    Ct[(size_t)(i * 32 + l0 + l) * KSEG + pq] = (f16_t)s;
  }
  // zero pad rows pq in [289,320)
  for (int v = tid; v < (KSEG - KTRUE) * 8; v += 256) {
    int pq = KTRUE + (v >> 3), l = v & 7;
    Ct[(size_t)(i * 32 + l0 + l) * KSEG + pq] = (f16_t)0.f;
  }
}

// ---------------------------------------------------------------------------
// Z[nt][KSEG] fp16 row-major: Z[nt,pq] = a'[p]*o'[q]; pads zero.
// ---------------------------------------------------------------------------
__global__ void build_Zt(const float* __restrict__ actions, const float* __restrict__ obss,
                         unsigned* __restrict__ Z, int n0) {
  __shared__ float sav[8][PDIM];
  __shared__ float sov[8][PDIM];
  const int r = threadIdx.x >> 5;
  const int c = threadIdx.x & 31;
  const int nt = blockIdx.x * 8 + r;
  const size_t gnt = (size_t)n0 * TSTEPS + nt;
  if (c < PDIM) {
    sav[r][c] = (c < 16) ? actions[gnt * 16 + c] : 1.f;
    sov[r][c] = (c < 16) ? obss[gnt * 16 + c] : 1.f;
  }
  __syncthreads();
  unsigned* zr = Z + (size_t)nt * (KSEG / 2);
#pragma unroll
  for (int u = 0; u < 5; ++u) {
    int col = u * 32 + c;        // uint col (2 fp16)
    int k0 = col * 2, k1 = k0 + 1;
    float z0 = (k0 < KTRUE) ? sav[r][k0 / PDIM] * sov[r][k0 % PDIM] : 0.f;
    float z1 = (k1 < KTRUE) ? sav[r][k1 / PDIM] * sov[r][k1 % PDIM] : 0.f;
    unsigned short h0 = __builtin_bit_cast(unsigned short, (f16_t)z0);
    unsigned short h1 = __builtin_bit_cast(unsigned short, (f16_t)z1);
    zr[col] = (unsigned)h0 | ((unsigned)h1 << 16);
  }
}

// ---------------------------------------------------------------------------
// 256x256 8-phase MFMA GEMM: M[nt,il](fp16) = Z x Ct^T over K=320 (fp16 in).
// 8 waves (2Mx4N), BK=64, 128KB static LDS dbuf, counted vmcnt(8), XOR swizzle.
// ---------------------------------------------------------------------------
__device__ __forceinline__ void gload16(const void* g, void* lds_) {
  __builtin_amdgcn_global_load_lds(
      (const __attribute__((address_space(1))) void*)g,
      (__attribute__((address_space(3))) void*)lds_, 16, 0, 0);
}

__global__ __launch_bounds__(512, 2) void gemm_M(const f16_t* __restrict__ Z,
                                                 const f16_t* __restrict__ Ct,
                                                 f16_t* __restrict__ Mout, int NTc) {
  __shared__ char lds[131072];
  const int nbm = NTc >> 8;
  const int nwg = nbm * 4;
  const int cpx = nwg >> 3;
  const int bid = blockIdx.x;
  const int wg = (bid & 7) * cpx + (bid >> 3);   // bijective XCD swizzle (nwg%8==0)
  const int bm = (wg >> 2) << 8;
  const int bn = (wg & 3) << 8;

  const int tid = threadIdx.x;
  const int w = tid >> 6, lane = tid & 63;
  const int wr = w >> 2, wc = w & 3;             // 2x4 wave grid
  const int lrow = lane & 15, lk = lane >> 4;
  const int u0 = lk ^ (lrow & 7);                // 16B-unit for ksub 0
  const int u1 = (lk + 4) ^ (lrow & 7);          // ksub 1

  const int srow = lane >> 3;
  const int jsrc = (lane & 7) ^ srow;            // pre-swizzled global 16B unit
  const char* Zb = (const char*)Z + (size_t)(bm + srow) * (KSEG * 2) + jsrc * 16;
  const char* Cb = (const char*)Ct + (size_t)(bn + srow) * (KSEG * 2) + jsrc * 16;

  auto stageA = [&](char* Ab, int sel, int kt) {
    const size_t ka = (size_t)kt * 128;
#pragma unroll
    for (int r = 0; r < 2; ++r) {
      int e = w * 2 + r;
      int c = sel ? (e + 8 + ((e >= 8) ? 8 : 0)) : (e + ((e >= 8) ? 8 : 0));
      gload16(Zb + (size_t)c * 8 * (KSEG * 2) + ka, Ab + c * 1024);
    }
  };
  auto stageB = [&](char* Bb, int half, int kt) {
    const size_t kb = (size_t)kt * 128;
#pragma unroll
    for (int r = 0; r < 2; ++r) {
      int c = w * 2 + r;
      gload16(Cb + (size_t)(half * 128 + c * 8) * (KSEG * 2) + kb,
              Bb + half * 16384 + c * 1024);
    }
  };

  f32x4 acc[8][4] = {};
  f16x8 af[4][2], bfr[4][2];

  // prologue: stage tiles 0 and 1
  stageA(lds, 0, 0); stageA(lds, 1, 0);
  stageB(lds + 32768, 0, 0); stageB(lds + 32768, 1, 0);
  stageA(lds + 65536, 0, 1); stageA(lds + 65536, 1, 1);
  stageB(lds + 98304, 0, 1); stageB(lds + 98304, 1, 1);
  asm volatile("s_waitcnt vmcnt(8)" ::: "memory"); SCHED0();
  SBAR(); SCHED0();

  for (int kt = 0; kt < NKT; ++kt) {
    const int p = kt & 1;
    char* Ap = lds + (p << 16);
    char* Bp = Ap + 32768;
    const bool doStage = (kt + 2 < NKT);

    // ---- P1: ds_read A-quarter0 (mf0-3) + B-all ----
#pragma unroll
    for (int mf = 0; mf < 4; ++mf) {
      const char* rp = Ap + (wr * 128 + mf * 16 + lrow) * 128;
      af[mf][0] = *(const f16x8*)(rp + u0 * 16);
      af[mf][1] = *(const f16x8*)(rp + u1 * 16);
    }
#pragma unroll
    for (int nf = 0; nf < 4; ++nf) {
      const char* cp = Bp + (wc * 64 + nf * 16 + lrow) * 128;
      bfr[nf][0] = *(const f16x8*)(cp + u0 * 16);
      bfr[nf][1] = *(const f16x8*)(cp + u1 * 16);
    }
    SCHED0();
    asm volatile("s_waitcnt lgkmcnt(0)" ::: "memory"); SCHED0();
    SBAR(); SCHED0();
    PRIO(1);
#pragma unroll
    for (int ks = 0; ks < 2; ++ks)
#pragma unroll
      for (int mf = 0; mf < 4; ++mf)
#pragma unroll
        for (int nf = 0; nf < 2; ++nf)
          acc[mf][nf] = __builtin_amdgcn_mfma_f32_16x16x32_f16(af[mf][ks], bfr[nf][ks], acc[mf][nf], 0, 0, 0);
    PRIO(0);
    SCHED0(); SBAR(); SCHED0();

    // ---- P2: stage tile kt+2 A-sel0 + B-both into buffer p (retired) ----
    if (doStage) { stageA(Ap, 0, kt + 2); stageB(Bp, 0, kt + 2); stageB(Bp, 1, kt + 2); }
    PRIO(1);
#pragma unroll
    for (int ks = 0; ks < 2; ++ks)
#pragma unroll
      for (int mf = 0; mf < 4; ++mf)
#pragma unroll
        for (int nf = 2; nf < 4; ++nf)
          acc[mf][nf] = __builtin_amdgcn_mfma_f32_16x16x32_f16(af[mf][ks], bfr[nf][ks], acc[mf][nf], 0, 0, 0);
    PRIO(0);
    SCHED0(); SBAR(); SCHED0();

    // ---- P3: ds_read A-quarter1 (mf4-7) ----
#pragma unroll
    for (int mf = 0; mf < 4; ++mf) {
      const char* rp = Ap + (wr * 128 + (mf + 4) * 16 + lrow) * 128;
      af[mf][0] = *(const f16x8*)(rp + u0 * 16);
      af[mf][1] = *(const f16x8*)(rp + u1 * 16);
    }
    SCHED0();
    asm volatile("s_waitcnt lgkmcnt(0)" ::: "memory"); SCHED0();
    SBAR(); SCHED0();
    PRIO(1);
#pragma unroll
    for (int ks = 0; ks < 2; ++ks)
#pragma unroll
      for (int mf = 0; mf < 4; ++mf)
#pragma unroll
        for (int nf = 0; nf < 2; ++nf)
          acc[mf + 4][nf] = __builtin_amdgcn_mfma_f32_16x16x32_f16(af[mf][ks], bfr[nf][ks], acc[mf + 4][nf], 0, 0, 0);
    PRIO(0);
    SCHED0(); SBAR(); SCHED0();

    // ---- P4: stage tile kt+2 A-sel1; counted vmcnt gate ----
    if (doStage) stageA(Ap, 1, kt + 2);
    PRIO(1);
#pragma unroll
    for (int ks = 0; ks < 2; ++ks)
#pragma unroll
      for (int mf = 0; mf < 4; ++mf)
#pragma unroll
        for (int nf = 2; nf < 4; ++nf)
          acc[mf + 4][nf] = __builtin_amdgcn_mfma_f32_16x16x32_f16(af[mf][ks], bfr[nf][ks], acc[mf + 4][nf], 0, 0, 0);
    PRIO(0);
    if (kt <= NKT - 3) {
      asm volatile("s_waitcnt vmcnt(8)" ::: "memory");
    } else if (kt == NKT - 2) {
      asm volatile("s_waitcnt vmcnt(0)" ::: "memory");
    }
    SCHED0(); SBAR(); SCHED0();
  }

  // epilogue: C/D layout col=lane&15, row=(lane>>4)*4+reg (verified R2/R5)
#pragma unroll
  for (int mf = 0; mf < 8; ++mf) {
    const int row0 = bm + wr * 128 + mf * 16 + lk * 4;
#pragma unroll
    for (int nf = 0; nf < 4; ++nf) {
      const int col = bn + wc * 64 + nf * 16 + lrow;
#pragma unroll
      for (int r2 = 0; r2 < 4; ++r2)
        Mout[(size_t)(row0 + r2) * MDIM + col] = (f16_t)acc[mf][nf][r2];
    }
  }
}

// ---------------------------------------------------------------------------
// Scan: tmp_{t+1}[l] = sum_i tmp_t[i]*M_t[i,l]; 1 wave/traj; M fp16.
// ---------------------------------------------------------------------------
__global__ void scan_kernel(const f16_t* __restrict__ M, const float* __restrict__ alpha,
                            const float* __restrict__ Omega, float* __restrict__ out, int n0) {
  const int l = threadIdx.x;
  const int ig = l >> 3, lg = l & 7;
  const char* Mn = (const char*)M + (size_t)blockIdx.x * TSTEPS * 2048 + (size_t)(ig * 128 + lg * 4) * 2;
  float s0 = alpha[ig * 4 + 0], s1 = alpha[ig * 4 + 1];
  float s2 = alpha[ig * 4 + 2], s3 = alpha[ig * 4 + 3];
  f16x4 b0[4], b1[4], b2[4], b3[4], b4[4], b5[4], b6[4], b7[4];

#define LOADB(B, t)                                     \
  { const char* p_ = Mn + (size_t)(t) * 2048;           \
    B[0] = *(const f16x4*)(p_);                         \
    B[1] = *(const f16x4*)(p_ + 64);                    \
    B[2] = *(const f16x4*)(p_ + 128);                   \
    B[3] = *(const f16x4*)(p_ + 192); }

  LOADB(b0, 0) LOADB(b1, 1) LOADB(b2, 2) LOADB(b3, 3)
  LOADB(b4, 4) LOADB(b5, 5) LOADB(b6, 6) LOADB(b7, 7)

#define STEPB(B, t)                                                    \
  { f32x4 part = __builtin_convertvector(B[0], f32x4) * s0;            \
    part += __builtin_convertvector(B[1], f32x4) * s1;                 \
    part += __builtin_convertvector(B[2], f32x4) * s2;                 \
    part += __builtin_convertvector(B[3], f32x4) * s3;                 \
    if ((t) + 8 < TSTEPS) LOADB(B, (t) + 8)                            \
    float p0 = part[0], p1 = part[1], p2 = part[2], p3 = part[3];      \
    p0 += __shfl_down(p0, 8, 64);  p1 += __shfl_down(p1, 8, 64);       \
    p2 += __shfl_down(p2, 8, 64);  p3 += __shfl_down(p3, 8, 64);       \
    p0 += __shfl_down(p0, 16, 64); p1 += __shfl_down(p1, 16, 64);      \
    p2 += __shfl_down(p2, 16, 64); p3 += __shfl_down(p3, 16, 64);      \
    p0 += __shfl_down(p0, 32, 64); p1 += __shfl_down(p1, 32, 64);      \
    p2 += __shfl_down(p2, 32, 64); p3 += __shfl_down(p3, 32, 64);      \
    s0 = __shfl(p0, ig, 64); s1 = __shfl(p1, ig, 64);                  \
    s2 = __shfl(p2, ig, 64); s3 = __shfl(p3, ig, 64); }

  for (int tt = 0; tt < TSTEPS / 8; ++tt) {
    const int t = tt * 8;
    STEPB(b0, t + 0) STEPB(b1, t + 1) STEPB(b2, t + 2) STEPB(b3, t + 3)
    STEPB(b4, t + 4) STEPB(b5, t + 5) STEPB(b6, t + 6) STEPB(b7, t + 7)
  }

  float v = 0.f;
  if (lg == 0)
    v = s0 * Omega[ig * 4 + 0] + s1 * Omega[ig * 4 + 1] +
        s2 * Omega[ig * 4 + 2] + s3 * Omega[ig * 4 + 3];
  v += __shfl_down(v, 32, 64);
  v += __shfl_down(v, 16, 64);
  v += __shfl_down(v, 8, 64);
  if (l == 0) out[n0 + blockIdx.x] = v;
}

// ---------------------------------------------------------------------------
extern "C" void kernel_launch(void* const* d_in, const int* in_sizes, int n_in,
                              void* d_out, int out_size, void* d_ws, size_t ws_size,
                              hipStream_t stream) {
  const float* actions = (const float*)d_in[0];
  const float* obss    = (const float*)d_in[1];
  const float* Wa      = (const float*)d_in[2];
  const float* ba      = (const float*)d_in[3];
  const float* Wo      = (const float*)d_in[4];
  const float* bo      = (const float*)d_in[5];
  const float* alpha   = (const float*)d_in[6];
  const float* A       = (const float*)d_in[7];
  const float* Omega   = (const float*)d_in[8];
  float* out = (float*)d_out;

  char* ws = (char*)d_ws;
  size_t fixed = ((size_t)KSEG * MDIM * 2 + 255) & ~(size_t)255;  // Ct 640KB

  int NC = NTRAJ;
  while (NC > 8) {
    size_t need = fixed + (size_t)NC * TSTEPS * ((size_t)KSEG * 2 + MDIM * 2);
    if (need <= ws_size) break;
    NC >>= 1;
  }
  const int NTc = NC * TSTEPS;
  f16_t*    Ct = (f16_t*)ws;
  unsigned* Zu = (unsigned*)(ws + fixed);
  f16_t*    M  = (f16_t*)(ws + fixed + (size_t)NTc * KSEG * 2);

  hipLaunchKernelGGL(build_Ct, dim3(128), dim3(256), 0, stream,
                     A, Wa, ba, Wo, bo, Ct);

  for (int n0 = 0; n0 < NTRAJ; n0 += NC) {
    hipLaunchKernelGGL(build_Zt, dim3(NTc / 8), dim3(256), 0, stream,
                       actions, obss, Zu, n0);
    hipLaunchKernelGGL(gemm_M, dim3((NTc >> 8) * 4), dim3(512), 0, stream,
                       (const f16_t*)Zu, Ct, M, NTc);
    hipLaunchKernelGGL(scan_kernel, dim3(NC), dim3(64), 0, stream,
                       M, alpha, Omega, out, n0);
  }
}

// Round 7
// 70.214 us; speedup vs baseline: 4.3611x; 1.4887x over previous
//
#include <hip/hip_runtime.h>

typedef _Float16 f16_t;
typedef f16_t f16x8 __attribute__((ext_vector_type(8)));
typedef f16_t f16x4 __attribute__((ext_vector_type(4)));
typedef float f32x4 __attribute__((ext_vector_type(4)));

#define R_ 32
#define NTRAJ 256
#define TSTEPS 128
#define PDIM 17
#define KTRUE 289
#define KSEG 320          // padded K (5 x 64)
#define NKT 5             // K-tiles
#define MDIM 1024
#define CHS 16            // chunk size (steps per chain wave)
#define NCH 8             // chunks per trajectory

#define SBAR() __builtin_amdgcn_s_barrier()
#define SCHED0() __builtin_amdgcn_sched_barrier(0)
#define PRIO(x) __builtin_amdgcn_s_setprio(x)

// ---------------------------------------------------------------------------
// Fused: Ct[il][pq] (fp16, row-major K-contig) from A, Wa', Wo'.
// ---------------------------------------------------------------------------
__global__ __launch_bounds__(256) void build_Ct(const float* __restrict__ A,
                                                const float* __restrict__ Wa,
                                                const float* __restrict__ ba,
                                                const float* __restrict__ Wo,
                                                const float* __restrict__ bo,
                                                f16_t* __restrict__ Ct) {
  __shared__ float Dls[PDIM][32][8];   // [p][k][l']
  __shared__ float Was[PDIM][33];
  __shared__ float Wos[PDIM][33];
  const int tid = threadIdx.x;
  const int i = blockIdx.x >> 2;
  const int l0 = (blockIdx.x & 3) * 8;

  for (int e = tid; e < PDIM * 32; e += 256) {
    int p = e >> 5, j = e & 31;
    Was[p][j] = (p < 16) ? Wa[p * 32 + j] : ba[j];
    Wos[p][j] = (p < 16) ? Wo[p * 32 + j] : bo[j];
  }
  const int k = tid >> 3, lp = tid & 7;
  float Dreg[PDIM] = {};
  const float* Abase = A + (size_t)i * 32768 + k * 32 + l0 + lp;
  __syncthreads();
#pragma unroll
  for (int j = 0; j < 32; ++j) {
    float a = Abase[(size_t)j * 1024];
#pragma unroll
    for (int p = 0; p < PDIM; ++p) Dreg[p] += Was[p][j] * a;
  }
#pragma unroll
  for (int p = 0; p < PDIM; ++p) Dls[p][k][lp] = Dreg[p];
  __syncthreads();

  for (int v = tid; v < KTRUE * 8; v += 256) {
    int pq = v >> 3, l = v & 7;
    int p = pq / PDIM, q = pq % PDIM;
    float s = 0.f;
#pragma unroll
    for (int kk = 0; kk < 32; ++kk) s += Wos[q][kk] * Dls[p][kk][l];
    Ct[(size_t)(i * 32 + l0 + l) * KSEG + pq] = (f16_t)s;
  }
  for (int v = tid; v < (KSEG - KTRUE) * 8; v += 256) {
    int pq = KTRUE + (v >> 3), l = v & 7;
    Ct[(size_t)(i * 32 + l0 + l) * KSEG + pq] = (f16_t)0.f;
  }
}

// ---------------------------------------------------------------------------
// Z[nt][KSEG] fp16 row-major: Z[nt,pq] = a'[p]*o'[q]; pads zero.
// ---------------------------------------------------------------------------
__global__ void build_Zt(const float* __restrict__ actions, const float* __restrict__ obss,
                         unsigned* __restrict__ Z, int n0) {
  __shared__ float sav[8][PDIM];
  __shared__ float sov[8][PDIM];
  const int r = threadIdx.x >> 5;
  const int c = threadIdx.x & 31;
  const int nt = blockIdx.x * 8 + r;
  const size_t gnt = (size_t)n0 * TSTEPS + nt;
  if (c < PDIM) {
    sav[r][c] = (c < 16) ? actions[gnt * 16 + c] : 1.f;
    sov[r][c] = (c < 16) ? obss[gnt * 16 + c] : 1.f;
  }
  __syncthreads();
  unsigned* zr = Z + (size_t)nt * (KSEG / 2);
#pragma unroll
  for (int u = 0; u < 5; ++u) {
    int col = u * 32 + c;
    int k0 = col * 2, k1 = k0 + 1;
    float z0 = (k0 < KTRUE) ? sav[r][k0 / PDIM] * sov[r][k0 % PDIM] : 0.f;
    float z1 = (k1 < KTRUE) ? sav[r][k1 / PDIM] * sov[r][k1 % PDIM] : 0.f;
    unsigned short h0 = __builtin_bit_cast(unsigned short, (f16_t)z0);
    unsigned short h1 = __builtin_bit_cast(unsigned short, (f16_t)z1);
    zr[col] = (unsigned)h0 | ((unsigned)h1 << 16);
  }
}

// ---------------------------------------------------------------------------
// 256x256 8-phase MFMA GEMM: M[nt,il](fp16) = Z x Ct^T over K=320 (fp16 in).
// ---------------------------------------------------------------------------
__device__ __forceinline__ void gload16(const void* g, void* lds_) {
  __builtin_amdgcn_global_load_lds(
      (const __attribute__((address_space(1))) void*)g,
      (__attribute__((address_space(3))) void*)lds_, 16, 0, 0);
}

__global__ __launch_bounds__(512, 2) void gemm_M(const f16_t* __restrict__ Z,
                                                 const f16_t* __restrict__ Ct,
                                                 f16_t* __restrict__ Mout, int NTc) {
  __shared__ char lds[131072];
  const int nbm = NTc >> 8;
  const int nwg = nbm * 4;
  const int cpx = nwg >> 3;
  const int bid = blockIdx.x;
  const int wg = (bid & 7) * cpx + (bid >> 3);   // bijective XCD swizzle (nwg%8==0)
  const int bm = (wg >> 2) << 8;
  const int bn = (wg & 3) << 8;

  const int tid = threadIdx.x;
  const int w = tid >> 6, lane = tid & 63;
  const int wr = w >> 2, wc = w & 3;             // 2x4 wave grid
  const int lrow = lane & 15, lk = lane >> 4;
  const int u0 = lk ^ (lrow & 7);
  const int u1 = (lk + 4) ^ (lrow & 7);

  const int srow = lane >> 3;
  const int jsrc = (lane & 7) ^ srow;
  const char* Zb = (const char*)Z + (size_t)(bm + srow) * (KSEG * 2) + jsrc * 16;
  const char* Cb = (const char*)Ct + (size_t)(bn + srow) * (KSEG * 2) + jsrc * 16;

  auto stageA = [&](char* Ab, int sel, int kt) {
    const size_t ka = (size_t)kt * 128;
#pragma unroll
    for (int r = 0; r < 2; ++r) {
      int e = w * 2 + r;
      int c = sel ? (e + 8 + ((e >= 8) ? 8 : 0)) : (e + ((e >= 8) ? 8 : 0));
      gload16(Zb + (size_t)c * 8 * (KSEG * 2) + ka, Ab + c * 1024);
    }
  };
  auto stageB = [&](char* Bb, int half, int kt) {
    const size_t kb = (size_t)kt * 128;
#pragma unroll
    for (int r = 0; r < 2; ++r) {
      int c = w * 2 + r;
      gload16(Cb + (size_t)(half * 128 + c * 8) * (KSEG * 2) + kb,
              Bb + half * 16384 + c * 1024);
    }
  };

  f32x4 acc[8][4] = {};
  f16x8 af[4][2], bfr[4][2];

  stageA(lds, 0, 0); stageA(lds, 1, 0);
  stageB(lds + 32768, 0, 0); stageB(lds + 32768, 1, 0);
  stageA(lds + 65536, 0, 1); stageA(lds + 65536, 1, 1);
  stageB(lds + 98304, 0, 1); stageB(lds + 98304, 1, 1);
  asm volatile("s_waitcnt vmcnt(8)" ::: "memory"); SCHED0();
  SBAR(); SCHED0();

  for (int kt = 0; kt < NKT; ++kt) {
    const int p = kt & 1;
    char* Ap = lds + (p << 16);
    char* Bp = Ap + 32768;
    const bool doStage = (kt + 2 < NKT);

    // ---- P1 ----
#pragma unroll
    for (int mf = 0; mf < 4; ++mf) {
      const char* rp = Ap + (wr * 128 + mf * 16 + lrow) * 128;
      af[mf][0] = *(const f16x8*)(rp + u0 * 16);
      af[mf][1] = *(const f16x8*)(rp + u1 * 16);
    }
#pragma unroll
    for (int nf = 0; nf < 4; ++nf) {
      const char* cp = Bp + (wc * 64 + nf * 16 + lrow) * 128;
      bfr[nf][0] = *(const f16x8*)(cp + u0 * 16);
      bfr[nf][1] = *(const f16x8*)(cp + u1 * 16);
    }
    SCHED0();
    asm volatile("s_waitcnt lgkmcnt(0)" ::: "memory"); SCHED0();
    SBAR(); SCHED0();
    PRIO(1);
#pragma unroll
    for (int ks = 0; ks < 2; ++ks)
#pragma unroll
      for (int mf = 0; mf < 4; ++mf)
#pragma unroll
        for (int nf = 0; nf < 2; ++nf)
          acc[mf][nf] = __builtin_amdgcn_mfma_f32_16x16x32_f16(af[mf][ks], bfr[nf][ks], acc[mf][nf], 0, 0, 0);
    PRIO(0);
    SCHED0(); SBAR(); SCHED0();

    // ---- P2 ----
    if (doStage) { stageA(Ap, 0, kt + 2); stageB(Bp, 0, kt + 2); stageB(Bp, 1, kt + 2); }
    PRIO(1);
#pragma unroll
    for (int ks = 0; ks < 2; ++ks)
#pragma unroll
      for (int mf = 0; mf < 4; ++mf)
#pragma unroll
        for (int nf = 2; nf < 4; ++nf)
          acc[mf][nf] = __builtin_amdgcn_mfma_f32_16x16x32_f16(af[mf][ks], bfr[nf][ks], acc[mf][nf], 0, 0, 0);
    PRIO(0);
    SCHED0(); SBAR(); SCHED0();

    // ---- P3 ----
#pragma unroll
    for (int mf = 0; mf < 4; ++mf) {
      const char* rp = Ap + (wr * 128 + (mf + 4) * 16 + lrow) * 128;
      af[mf][0] = *(const f16x8*)(rp + u0 * 16);
      af[mf][1] = *(const f16x8*)(rp + u1 * 16);
    }
    SCHED0();
    asm volatile("s_waitcnt lgkmcnt(0)" ::: "memory"); SCHED0();
    SBAR(); SCHED0();
    PRIO(1);
#pragma unroll
    for (int ks = 0; ks < 2; ++ks)
#pragma unroll
      for (int mf = 0; mf < 4; ++mf)
#pragma unroll
        for (int nf = 0; nf < 2; ++nf)
          acc[mf + 4][nf] = __builtin_amdgcn_mfma_f32_16x16x32_f16(af[mf][ks], bfr[nf][ks], acc[mf + 4][nf], 0, 0, 0);
    PRIO(0);
    SCHED0(); SBAR(); SCHED0();

    // ---- P4 ----
    if (doStage) stageA(Ap, 1, kt + 2);
    PRIO(1);
#pragma unroll
    for (int ks = 0; ks < 2; ++ks)
#pragma unroll
      for (int mf = 0; mf < 4; ++mf)
#pragma unroll
        for (int nf = 2; nf < 4; ++nf)
          acc[mf + 4][nf] = __builtin_amdgcn_mfma_f32_16x16x32_f16(af[mf][ks], bfr[nf][ks], acc[mf + 4][nf], 0, 0, 0);
    PRIO(0);
    if (kt <= NKT - 3) {
      asm volatile("s_waitcnt vmcnt(8)" ::: "memory");
    } else if (kt == NKT - 2) {
      asm volatile("s_waitcnt vmcnt(0)" ::: "memory");
    }
    SCHED0(); SBAR(); SCHED0();
  }

#pragma unroll
  for (int mf = 0; mf < 8; ++mf) {
    const int row0 = bm + wr * 128 + mf * 16 + lk * 4;
#pragma unroll
    for (int nf = 0; nf < 4; ++nf) {
      const int col = bn + wc * 64 + nf * 16 + lrow;
#pragma unroll
      for (int r2 = 0; r2 < 4; ++r2)
        Mout[(size_t)(row0 + r2) * MDIM + col] = (f16_t)acc[mf][nf][r2];
    }
  }
}

// ---------------------------------------------------------------------------
// Phase A: chunk chain products. 1 wave per chunk of 16 steps:
// P_c = M_{16c} * M_{16c+1} * ... * M_{16c+15}  (fp16 in, fp32 MFMA accum,
// fp16 intermediates via wave-private LDS round-trip; pad-80B rows).
// ---------------------------------------------------------------------------
__global__ __launch_bounds__(256) void chain_kernel(const f16_t* __restrict__ M,
                                                    f16_t* __restrict__ Pc) {
  __shared__ char buf[4][5120];  // per wave: Q [32 rows][80B] @0, MT @2560
  const int wid = threadIdx.x >> 6, lane = threadIdx.x & 63;
  char* Qb = buf[wid];
  char* MT = buf[wid] + 2560;
  const int cid = blockIdx.x * 4 + wid;          // chunk id; 16 consecutive nt rows
  const char* Mb = (const char*)M + (size_t)cid * CHS * 2048;

  const int il = lane >> 1, c0 = (lane & 1) << 4;  // load/transpose mapping
  const int lr = lane & 15, lg = lane >> 4;        // frag mapping
  const char* mp = Mb + il * 64 + c0 * 2;

  // Q = M_0 (row-major, stride 80B)
  f16x8 na = *(const f16x8*)(mp);
  f16x8 nb = *(const f16x8*)(mp + 16);
  *(f16x8*)(Qb + il * 80 + c0 * 2) = na;
  *(f16x8*)(Qb + il * 80 + c0 * 2 + 16) = nb;
  // preload M_1
  na = *(const f16x8*)(mp + 2048);
  nb = *(const f16x8*)(mp + 2048 + 16);

  const f32x4 z = {0.f, 0.f, 0.f, 0.f};
  f32x4 a00 = z, a01 = z, a10 = z, a11 = z;
  f16x8 ma, mb2;

  for (int t = 1; t < CHS; ++t) {
    // transpose-write M_t -> MT[c][k] = M[k][c]
#pragma unroll
    for (int j = 0; j < 8; ++j) {
      *(f16_t*)(MT + (c0 + j) * 80 + il * 2) = na[j];
      *(f16_t*)(MT + (c0 + 8 + j) * 80 + il * 2) = nb[j];
    }
    if (t < CHS - 1) {  // prefetch M_{t+1}
      ma = *(const f16x8*)(mp + (size_t)(t + 1) * 2048);
      mb2 = *(const f16x8*)(mp + (size_t)(t + 1) * 2048 + 16);
    }
    // A-frags: Q rows (row=lr+16a, k contig at lg*8); B-frags: MT rows (col=lr+16b)
    f16x8 af0 = *(const f16x8*)(Qb + lr * 80 + lg * 16);
    f16x8 af1 = *(const f16x8*)(Qb + (16 + lr) * 80 + lg * 16);
    f16x8 bf0 = *(const f16x8*)(MT + lr * 80 + lg * 16);
    f16x8 bf1 = *(const f16x8*)(MT + (16 + lr) * 80 + lg * 16);
    a00 = __builtin_amdgcn_mfma_f32_16x16x32_f16(af0, bf0, z, 0, 0, 0);
    a01 = __builtin_amdgcn_mfma_f32_16x16x32_f16(af0, bf1, z, 0, 0, 0);
    a10 = __builtin_amdgcn_mfma_f32_16x16x32_f16(af1, bf0, z, 0, 0, 0);
    a11 = __builtin_amdgcn_mfma_f32_16x16x32_f16(af1, bf1, z, 0, 0, 0);
    if (t < CHS - 1) {
      // write Q back: D-layout row=lg*4+r2 (+16a), col=lr (+16b)
#pragma unroll
      for (int r2 = 0; r2 < 4; ++r2) {
        *(f16_t*)(Qb + (lg * 4 + r2) * 80 + lr * 2)              = (f16_t)a00[r2];
        *(f16_t*)(Qb + (lg * 4 + r2) * 80 + (16 + lr) * 2)       = (f16_t)a01[r2];
        *(f16_t*)(Qb + (16 + lg * 4 + r2) * 80 + lr * 2)         = (f16_t)a10[r2];
        *(f16_t*)(Qb + (16 + lg * 4 + r2) * 80 + (16 + lr) * 2)  = (f16_t)a11[r2];
      }
      na = ma; nb = mb2;
    }
  }
  // store P_c (row-major [32][32] fp16)
  f16_t* pc = Pc + (size_t)cid * 1024;
#pragma unroll
  for (int r2 = 0; r2 < 4; ++r2) {
    pc[(lg * 4 + r2) * 32 + lr]           = (f16_t)a00[r2];
    pc[(lg * 4 + r2) * 32 + 16 + lr]      = (f16_t)a01[r2];
    pc[(16 + lg * 4 + r2) * 32 + lr]      = (f16_t)a10[r2];
    pc[(16 + lg * 4 + r2) * 32 + 16 + lr] = (f16_t)a11[r2];
  }
}

// ---------------------------------------------------------------------------
// Phase B: tmp = alpha; for c in 0..7: tmp = tmp * P_c; out = tmp . Omega
// 1 wave per trajectory; all 8 P_c preloaded.
// ---------------------------------------------------------------------------
__global__ void finish_kernel(const f16_t* __restrict__ Pc, const float* __restrict__ alpha,
                              const float* __restrict__ Omega, float* __restrict__ out, int n0) {
  const int l = threadIdx.x;
  const int ig = l >> 3, lg = l & 7;
  const char* Pn = (const char*)Pc + (size_t)blockIdx.x * NCH * 2048 + (size_t)(ig * 128 + lg * 4) * 2;
  float s0 = alpha[ig * 4 + 0], s1 = alpha[ig * 4 + 1];
  float s2 = alpha[ig * 4 + 2], s3 = alpha[ig * 4 + 3];
  f16x4 b0[4], b1[4], b2[4], b3[4], b4[4], b5[4], b6[4], b7[4];

#define LOADB(B, t)                                     \
  { const char* p_ = Pn + (size_t)(t) * 2048;           \
    B[0] = *(const f16x4*)(p_);                         \
    B[1] = *(const f16x4*)(p_ + 64);                    \
    B[2] = *(const f16x4*)(p_ + 128);                   \
    B[3] = *(const f16x4*)(p_ + 192); }

  LOADB(b0, 0) LOADB(b1, 1) LOADB(b2, 2) LOADB(b3, 3)
  LOADB(b4, 4) LOADB(b5, 5) LOADB(b6, 6) LOADB(b7, 7)

#define STEPB(B)                                                       \
  { f32x4 part = __builtin_convertvector(B[0], f32x4) * s0;            \
    part += __builtin_convertvector(B[1], f32x4) * s1;                 \
    part += __builtin_convertvector(B[2], f32x4) * s2;                 \
    part += __builtin_convertvector(B[3], f32x4) * s3;                 \
    float p0 = part[0], p1 = part[1], p2 = part[2], p3 = part[3];      \
    p0 += __shfl_down(p0, 8, 64);  p1 += __shfl_down(p1, 8, 64);       \
    p2 += __shfl_down(p2, 8, 64);  p3 += __shfl_down(p3, 8, 64);       \
    p0 += __shfl_down(p0, 16, 64); p1 += __shfl_down(p1, 16, 64);      \
    p2 += __shfl_down(p2, 16, 64); p3 += __shfl_down(p3, 16, 64);      \
    p0 += __shfl_down(p0, 32, 64); p1 += __shfl_down(p1, 32, 64);      \
    p2 += __shfl_down(p2, 32, 64); p3 += __shfl_down(p3, 32, 64);      \
    s0 = __shfl(p0, ig, 64); s1 = __shfl(p1, ig, 64);                  \
    s2 = __shfl(p2, ig, 64); s3 = __shfl(p3, ig, 64); }

  STEPB(b0) STEPB(b1) STEPB(b2) STEPB(b3)
  STEPB(b4) STEPB(b5) STEPB(b6) STEPB(b7)

  float v = 0.f;
  if (lg == 0)
    v = s0 * Omega[ig * 4 + 0] + s1 * Omega[ig * 4 + 1] +
        s2 * Omega[ig * 4 + 2] + s3 * Omega[ig * 4 + 3];
  v += __shfl_down(v, 32, 64);
  v += __shfl_down(v, 16, 64);
  v += __shfl_down(v, 8, 64);
  if (l == 0) out[n0 + blockIdx.x] = v;
}

// ---------------------------------------------------------------------------
extern "C" void kernel_launch(void* const* d_in, const int* in_sizes, int n_in,
                              void* d_out, int out_size, void* d_ws, size_t ws_size,
                              hipStream_t stream) {
  const float* actions = (const float*)d_in[0];
  const float* obss    = (const float*)d_in[1];
  const float* Wa      = (const float*)d_in[2];
  const float* ba      = (const float*)d_in[3];
  const float* Wo      = (const float*)d_in[4];
  const float* bo      = (const float*)d_in[5];
  const float* alpha   = (const float*)d_in[6];
  const float* A       = (const float*)d_in[7];
  const float* Omega   = (const float*)d_in[8];
  float* out = (float*)d_out;

  char* ws = (char*)d_ws;
  size_t fixed = ((size_t)KSEG * MDIM * 2 + 255) & ~(size_t)255;  // Ct 640KB

  int NC = NTRAJ;
  while (NC > 8) {
    size_t need = fixed + (size_t)NC * TSTEPS * ((size_t)KSEG * 2 + MDIM * 2);
    if (need <= ws_size) break;
    NC >>= 1;
  }
  const int NTc = NC * TSTEPS;
  f16_t*    Ct = (f16_t*)ws;
  unsigned* Zu = (unsigned*)(ws + fixed);
  f16_t*    M  = (f16_t*)(ws + fixed + (size_t)NTc * KSEG * 2);
  // Pc overlays Zu (Zu dead after gemm_M; Pc = NC*8*2KB <= Zu = NTc*640B)
  f16_t*    Pc = (f16_t*)(ws + fixed);

  hipLaunchKernelGGL(build_Ct, dim3(128), dim3(256), 0, stream,
                     A, Wa, ba, Wo, bo, Ct);

  for (int n0 = 0; n0 < NTRAJ; n0 += NC) {
    hipLaunchKernelGGL(build_Zt, dim3(NTc / 8), dim3(256), 0, stream,
                       actions, obss, Zu, n0);
    hipLaunchKernelGGL(gemm_M, dim3((NTc >> 8) * 4), dim3(512), 0, stream,
                       (const f16_t*)Zu, Ct, M, NTc);
    hipLaunchKernelGGL(chain_kernel, dim3(NC * NCH / 4), dim3(256), 0, stream,
                       M, Pc);
    hipLaunchKernelGGL(finish_kernel, dim3(NC), dim3(64), 0, stream,
                       Pc, alpha, Omega, out, n0);
  }
}

// Round 8
// 69.702 us; speedup vs baseline: 4.3931x; 1.0074x over previous
//
#include <hip/hip_runtime.h>

typedef _Float16 f16_t;
typedef f16_t f16x8 __attribute__((ext_vector_type(8)));
typedef f16_t f16x4 __attribute__((ext_vector_type(4)));
typedef float f32x4 __attribute__((ext_vector_type(4)));

#define R_ 32
#define NTRAJ 256
#define TSTEPS 128
#define PDIM 17
#define KTRUE 289
#define KSEG 320          // padded K (5 x 64)
#define NKT 5             // K-tiles
#define MDIM 1024
#define CHS 8             // chunk size (steps per chain wave)
#define NCH 16            // chunks per trajectory

#define SBAR() __builtin_amdgcn_s_barrier()
#define SCHED0() __builtin_amdgcn_sched_barrier(0)
#define PRIO(x) __builtin_amdgcn_s_setprio(x)

// ---------------------------------------------------------------------------
// Merged prep kernel. Blocks [0,128): Ct[il][pq] (fp16, K-contig) from A,Wa',Wo'.
// Blocks [128, 128+NTc/8): Z[nt][KSEG] fp16, Z[nt,pq] = a'[p]*o'[q].
// ---------------------------------------------------------------------------
__global__ __launch_bounds__(256) void build_CtZt(const float* __restrict__ A,
                                                  const float* __restrict__ Wa,
                                                  const float* __restrict__ ba,
                                                  const float* __restrict__ Wo,
                                                  const float* __restrict__ bo,
                                                  const float* __restrict__ actions,
                                                  const float* __restrict__ obss,
                                                  f16_t* __restrict__ Ct,
                                                  unsigned* __restrict__ Z, int n0) {
  __shared__ float Dls[PDIM][32][8];   // [p][k][l']   (Ct role)
  __shared__ float Was[PDIM][33];
  __shared__ float Wos[PDIM][33];
  __shared__ float sav[8][PDIM];       // (Zt role)
  __shared__ float sov[8][PDIM];
  const int tid = threadIdx.x;

  if (blockIdx.x < 128) {
    const int i = blockIdx.x >> 2;
    const int l0 = (blockIdx.x & 3) * 8;
    for (int e = tid; e < PDIM * 32; e += 256) {
      int p = e >> 5, j = e & 31;
      Was[p][j] = (p < 16) ? Wa[p * 32 + j] : ba[j];
      Wos[p][j] = (p < 16) ? Wo[p * 32 + j] : bo[j];
    }
    const int k = tid >> 3, lp = tid & 7;
    float Dreg[PDIM] = {};
    const float* Abase = A + (size_t)i * 32768 + k * 32 + l0 + lp;
    __syncthreads();
#pragma unroll
    for (int j = 0; j < 32; ++j) {
      float a = Abase[(size_t)j * 1024];
#pragma unroll
      for (int p = 0; p < PDIM; ++p) Dreg[p] += Was[p][j] * a;
    }
#pragma unroll
    for (int p = 0; p < PDIM; ++p) Dls[p][k][lp] = Dreg[p];
    __syncthreads();

    for (int v = tid; v < KTRUE * 8; v += 256) {
      int pq = v >> 3, l = v & 7;
      int p = pq / PDIM, q = pq % PDIM;
      float s = 0.f;
#pragma unroll
      for (int kk = 0; kk < 32; ++kk) s += Wos[q][kk] * Dls[p][kk][l];
      Ct[(size_t)(i * 32 + l0 + l) * KSEG + pq] = (f16_t)s;
    }
    for (int v = tid; v < (KSEG - KTRUE) * 8; v += 256) {
      int pq = KTRUE + (v >> 3), l = v & 7;
      Ct[(size_t)(i * 32 + l0 + l) * KSEG + pq] = (f16_t)0.f;
    }
  } else {
    const int zbid = blockIdx.x - 128;
    const int r = tid >> 5;
    const int c = tid & 31;
    const int nt = zbid * 8 + r;
    const size_t gnt = (size_t)n0 * TSTEPS + nt;
    if (c < PDIM) {
      sav[r][c] = (c < 16) ? actions[gnt * 16 + c] : 1.f;
      sov[r][c] = (c < 16) ? obss[gnt * 16 + c] : 1.f;
    }
    __syncthreads();
    unsigned* zr = Z + (size_t)nt * (KSEG / 2);
#pragma unroll
    for (int u = 0; u < 5; ++u) {
      int col = u * 32 + c;
      int k0 = col * 2, k1 = k0 + 1;
      float z0 = (k0 < KTRUE) ? sav[r][k0 / PDIM] * sov[r][k0 % PDIM] : 0.f;
      float z1 = (k1 < KTRUE) ? sav[r][k1 / PDIM] * sov[r][k1 % PDIM] : 0.f;
      unsigned short h0 = __builtin_bit_cast(unsigned short, (f16_t)z0);
      unsigned short h1 = __builtin_bit_cast(unsigned short, (f16_t)z1);
      zr[col] = (unsigned)h0 | ((unsigned)h1 << 16);
    }
  }
}

// ---------------------------------------------------------------------------
// 256x256 8-phase MFMA GEMM: M[nt,il](fp16) = Z x Ct^T over K=320 (fp16 in).
// (unchanged from R7 — verified)
// ---------------------------------------------------------------------------
__device__ __forceinline__ void gload16(const void* g, void* lds_) {
  __builtin_amdgcn_global_load_lds(
      (const __attribute__((address_space(1))) void*)g,
      (__attribute__((address_space(3))) void*)lds_, 16, 0, 0);
}

__global__ __launch_bounds__(512, 2) void gemm_M(const f16_t* __restrict__ Z,
                                                 const f16_t* __restrict__ Ct,
                                                 f16_t* __restrict__ Mout, int NTc) {
  __shared__ char lds[131072];
  const int nbm = NTc >> 8;
  const int nwg = nbm * 4;
  const int cpx = nwg >> 3;
  const int bid = blockIdx.x;
  const int wg = (bid & 7) * cpx + (bid >> 3);   // bijective XCD swizzle (nwg%8==0)
  const int bm = (wg >> 2) << 8;
  const int bn = (wg & 3) << 8;

  const int tid = threadIdx.x;
  const int w = tid >> 6, lane = tid & 63;
  const int wr = w >> 2, wc = w & 3;             // 2x4 wave grid
  const int lrow = lane & 15, lk = lane >> 4;
  const int u0 = lk ^ (lrow & 7);
  const int u1 = (lk + 4) ^ (lrow & 7);

  const int srow = lane >> 3;
  const int jsrc = (lane & 7) ^ srow;
  const char* Zb = (const char*)Z + (size_t)(bm + srow) * (KSEG * 2) + jsrc * 16;
  const char* Cb = (const char*)Ct + (size_t)(bn + srow) * (KSEG * 2) + jsrc * 16;

  auto stageA = [&](char* Ab, int sel, int kt) {
    const size_t ka = (size_t)kt * 128;
#pragma unroll
    for (int r = 0; r < 2; ++r) {
      int e = w * 2 + r;
      int c = sel ? (e + 8 + ((e >= 8) ? 8 : 0)) : (e + ((e >= 8) ? 8 : 0));
      gload16(Zb + (size_t)c * 8 * (KSEG * 2) + ka, Ab + c * 1024);
    }
  };
  auto stageB = [&](char* Bb, int half, int kt) {
    const size_t kb = (size_t)kt * 128;
#pragma unroll
    for (int r = 0; r < 2; ++r) {
      int c = w * 2 + r;
      gload16(Cb + (size_t)(half * 128 + c * 8) * (KSEG * 2) + kb,
              Bb + half * 16384 + c * 1024);
    }
  };

  f32x4 acc[8][4] = {};
  f16x8 af[4][2], bfr[4][2];

  stageA(lds, 0, 0); stageA(lds, 1, 0);
  stageB(lds + 32768, 0, 0); stageB(lds + 32768, 1, 0);
  stageA(lds + 65536, 0, 1); stageA(lds + 65536, 1, 1);
  stageB(lds + 98304, 0, 1); stageB(lds + 98304, 1, 1);
  asm volatile("s_waitcnt vmcnt(8)" ::: "memory"); SCHED0();
  SBAR(); SCHED0();

  for (int kt = 0; kt < NKT; ++kt) {
    const int p = kt & 1;
    char* Ap = lds + (p << 16);
    char* Bp = Ap + 32768;
    const bool doStage = (kt + 2 < NKT);

    // ---- P1 ----
#pragma unroll
    for (int mf = 0; mf < 4; ++mf) {
      const char* rp = Ap + (wr * 128 + mf * 16 + lrow) * 128;
      af[mf][0] = *(const f16x8*)(rp + u0 * 16);
      af[mf][1] = *(const f16x8*)(rp + u1 * 16);
    }
#pragma unroll
    for (int nf = 0; nf < 4; ++nf) {
      const char* cp = Bp + (wc * 64 + nf * 16 + lrow) * 128;
      bfr[nf][0] = *(const f16x8*)(cp + u0 * 16);
      bfr[nf][1] = *(const f16x8*)(cp + u1 * 16);
    }
    SCHED0();
    asm volatile("s_waitcnt lgkmcnt(0)" ::: "memory"); SCHED0();
    SBAR(); SCHED0();
    PRIO(1);
#pragma unroll
    for (int ks = 0; ks < 2; ++ks)
#pragma unroll
      for (int mf = 0; mf < 4; ++mf)
#pragma unroll
        for (int nf = 0; nf < 2; ++nf)
          acc[mf][nf] = __builtin_amdgcn_mfma_f32_16x16x32_f16(af[mf][ks], bfr[nf][ks], acc[mf][nf], 0, 0, 0);
    PRIO(0);
    SCHED0(); SBAR(); SCHED0();

    // ---- P2 ----
    if (doStage) { stageA(Ap, 0, kt + 2); stageB(Bp, 0, kt + 2); stageB(Bp, 1, kt + 2); }
    PRIO(1);
#pragma unroll
    for (int ks = 0; ks < 2; ++ks)
#pragma unroll
      for (int mf = 0; mf < 4; ++mf)
#pragma unroll
        for (int nf = 2; nf < 4; ++nf)
          acc[mf][nf] = __builtin_amdgcn_mfma_f32_16x16x32_f16(af[mf][ks], bfr[nf][ks], acc[mf][nf], 0, 0, 0);
    PRIO(0);
    SCHED0(); SBAR(); SCHED0();

    // ---- P3 ----
#pragma unroll
    for (int mf = 0; mf < 4; ++mf) {
      const char* rp = Ap + (wr * 128 + (mf + 4) * 16 + lrow) * 128;
      af[mf][0] = *(const f16x8*)(rp + u0 * 16);
      af[mf][1] = *(const f16x8*)(rp + u1 * 16);
    }
    SCHED0();
    asm volatile("s_waitcnt lgkmcnt(0)" ::: "memory"); SCHED0();
    SBAR(); SCHED0();
    PRIO(1);
#pragma unroll
    for (int ks = 0; ks < 2; ++ks)
#pragma unroll
      for (int mf = 0; mf < 4; ++mf)
#pragma unroll
        for (int nf = 0; nf < 2; ++nf)
          acc[mf + 4][nf] = __builtin_amdgcn_mfma_f32_16x16x32_f16(af[mf][ks], bfr[nf][ks], acc[mf + 4][nf], 0, 0, 0);
    PRIO(0);
    SCHED0(); SBAR(); SCHED0();

    // ---- P4 ----
    if (doStage) stageA(Ap, 1, kt + 2);
    PRIO(1);
#pragma unroll
    for (int ks = 0; ks < 2; ++ks)
#pragma unroll
      for (int mf = 0; mf < 4; ++mf)
#pragma unroll
        for (int nf = 2; nf < 4; ++nf)
          acc[mf + 4][nf] = __builtin_amdgcn_mfma_f32_16x16x32_f16(af[mf][ks], bfr[nf][ks], acc[mf + 4][nf], 0, 0, 0);
    PRIO(0);
    if (kt <= NKT - 3) {
      asm volatile("s_waitcnt vmcnt(8)" ::: "memory");
    } else if (kt == NKT - 2) {
      asm volatile("s_waitcnt vmcnt(0)" ::: "memory");
    }
    SCHED0(); SBAR(); SCHED0();
  }

#pragma unroll
  for (int mf = 0; mf < 8; ++mf) {
    const int row0 = bm + wr * 128 + mf * 16 + lk * 4;
#pragma unroll
    for (int nf = 0; nf < 4; ++nf) {
      const int col = bn + wc * 64 + nf * 16 + lrow;
#pragma unroll
      for (int r2 = 0; r2 < 4; ++r2)
        Mout[(size_t)(row0 + r2) * MDIM + col] = (f16_t)acc[mf][nf][r2];
    }
  }
}

// ---------------------------------------------------------------------------
// Merged chain+finish: 1 block (16 waves) per trajectory.
// Wave w computes P_w = M_{8w} * ... * M_{8w+7} (fp16 in, fp32 MFMA accum,
// fp16 LDS roundtrip, pad-80B rows); products to LDS; wave 0 folds
// tmp = alpha * P_0 * ... * P_15, out = tmp . Omega.
// ---------------------------------------------------------------------------
__global__ __launch_bounds__(1024) void chainfin(const f16_t* __restrict__ M,
                                                 const float* __restrict__ alpha,
                                                 const float* __restrict__ Omega,
                                                 float* __restrict__ out, int n0) {
  __shared__ char buf[16][5120];       // per wave: Q [32][80B] @0, MT @2560
  __shared__ f16_t sPc[NCH][1024];     // chunk products, row-major [32][32]
  const int wid = threadIdx.x >> 6, lane = threadIdx.x & 63;
  char* Qb = buf[wid];
  char* MT = buf[wid] + 2560;
  const char* Mb = (const char*)M + ((size_t)blockIdx.x * TSTEPS + wid * CHS) * 2048;

  const int il = lane >> 1, c0 = (lane & 1) << 4;  // load/transpose mapping
  const int lr = lane & 15, lg = lane >> 4;        // frag mapping
  const char* mp = Mb + il * 64 + c0 * 2;

  // Q = M_0 (row-major, stride 80B)
  f16x8 na = *(const f16x8*)(mp);
  f16x8 nb = *(const f16x8*)(mp + 16);
  *(f16x8*)(Qb + il * 80 + c0 * 2) = na;
  *(f16x8*)(Qb + il * 80 + c0 * 2 + 16) = nb;
  // preload M_1
  na = *(const f16x8*)(mp + 2048);
  nb = *(const f16x8*)(mp + 2048 + 16);

  const f32x4 z = {0.f, 0.f, 0.f, 0.f};
  f32x4 a00 = z, a01 = z, a10 = z, a11 = z;
  f16x8 ma, mb2;

  for (int t = 1; t < CHS; ++t) {
    // transpose-write M_t -> MT[c][k] = M[k][c]
#pragma unroll
    for (int j = 0; j < 8; ++j) {
      *(f16_t*)(MT + (c0 + j) * 80 + il * 2) = na[j];
      *(f16_t*)(MT + (c0 + 8 + j) * 80 + il * 2) = nb[j];
    }
    if (t < CHS - 1) {  // prefetch M_{t+1}
      ma = *(const f16x8*)(mp + (size_t)(t + 1) * 2048);
      mb2 = *(const f16x8*)(mp + (size_t)(t + 1) * 2048 + 16);
    }
    f16x8 af0 = *(const f16x8*)(Qb + lr * 80 + lg * 16);
    f16x8 af1 = *(const f16x8*)(Qb + (16 + lr) * 80 + lg * 16);
    f16x8 bf0 = *(const f16x8*)(MT + lr * 80 + lg * 16);
    f16x8 bf1 = *(const f16x8*)(MT + (16 + lr) * 80 + lg * 16);
    a00 = __builtin_amdgcn_mfma_f32_16x16x32_f16(af0, bf0, z, 0, 0, 0);
    a01 = __builtin_amdgcn_mfma_f32_16x16x32_f16(af0, bf1, z, 0, 0, 0);
    a10 = __builtin_amdgcn_mfma_f32_16x16x32_f16(af1, bf0, z, 0, 0, 0);
    a11 = __builtin_amdgcn_mfma_f32_16x16x32_f16(af1, bf1, z, 0, 0, 0);
    if (t < CHS - 1) {
      // write Q back: D-layout row=lg*4+r2 (+16a), col=lr (+16b)
#pragma unroll
      for (int r2 = 0; r2 < 4; ++r2) {
        *(f16_t*)(Qb + (lg * 4 + r2) * 80 + lr * 2)              = (f16_t)a00[r2];
        *(f16_t*)(Qb + (lg * 4 + r2) * 80 + (16 + lr) * 2)       = (f16_t)a01[r2];
        *(f16_t*)(Qb + (16 + lg * 4 + r2) * 80 + lr * 2)         = (f16_t)a10[r2];
        *(f16_t*)(Qb + (16 + lg * 4 + r2) * 80 + (16 + lr) * 2)  = (f16_t)a11[r2];
      }
      na = ma; nb = mb2;
    }
  }
  // store P_w into LDS (row-major [32][32])
  f16_t* pc = sPc[wid];
#pragma unroll
  for (int r2 = 0; r2 < 4; ++r2) {
    pc[(lg * 4 + r2) * 32 + lr]           = (f16_t)a00[r2];
    pc[(lg * 4 + r2) * 32 + 16 + lr]      = (f16_t)a01[r2];
    pc[(16 + lg * 4 + r2) * 32 + lr]      = (f16_t)a10[r2];
    pc[(16 + lg * 4 + r2) * 32 + 16 + lr] = (f16_t)a11[r2];
  }
  __syncthreads();

  if (wid == 0) {
    const int ig = lane >> 3, lgf = lane & 7;
    float s0 = alpha[ig * 4 + 0], s1 = alpha[ig * 4 + 1];
    float s2 = alpha[ig * 4 + 2], s3 = alpha[ig * 4 + 3];
    for (int c = 0; c < NCH; ++c) {
      const f16_t* pn = &sPc[c][ig * 128 + lgf * 4];
      f32x4 part = __builtin_convertvector(*(const f16x4*)(pn), f32x4) * s0;
      part += __builtin_convertvector(*(const f16x4*)(pn + 32), f32x4) * s1;
      part += __builtin_convertvector(*(const f16x4*)(pn + 64), f32x4) * s2;
      part += __builtin_convertvector(*(const f16x4*)(pn + 96), f32x4) * s3;
      float p0 = part[0], p1 = part[1], p2 = part[2], p3 = part[3];
      p0 += __shfl_down(p0, 8, 64);  p1 += __shfl_down(p1, 8, 64);
      p2 += __shfl_down(p2, 8, 64);  p3 += __shfl_down(p3, 8, 64);
      p0 += __shfl_down(p0, 16, 64); p1 += __shfl_down(p1, 16, 64);
      p2 += __shfl_down(p2, 16, 64); p3 += __shfl_down(p3, 16, 64);
      p0 += __shfl_down(p0, 32, 64); p1 += __shfl_down(p1, 32, 64);
      p2 += __shfl_down(p2, 32, 64); p3 += __shfl_down(p3, 32, 64);
      s0 = __shfl(p0, ig, 64); s1 = __shfl(p1, ig, 64);
      s2 = __shfl(p2, ig, 64); s3 = __shfl(p3, ig, 64);
    }
    float v = 0.f;
    if (lgf == 0)
      v = s0 * Omega[ig * 4 + 0] + s1 * Omega[ig * 4 + 1] +
          s2 * Omega[ig * 4 + 2] + s3 * Omega[ig * 4 + 3];
    v += __shfl_down(v, 32, 64);
    v += __shfl_down(v, 16, 64);
    v += __shfl_down(v, 8, 64);
    if (lane == 0) out[n0 + blockIdx.x] = v;
  }
}

// ---------------------------------------------------------------------------
extern "C" void kernel_launch(void* const* d_in, const int* in_sizes, int n_in,
                              void* d_out, int out_size, void* d_ws, size_t ws_size,
                              hipStream_t stream) {
  const float* actions = (const float*)d_in[0];
  const float* obss    = (const float*)d_in[1];
  const float* Wa      = (const float*)d_in[2];
  const float* ba      = (const float*)d_in[3];
  const float* Wo      = (const float*)d_in[4];
  const float* bo      = (const float*)d_in[5];
  const float* alpha   = (const float*)d_in[6];
  const float* A       = (const float*)d_in[7];
  const float* Omega   = (const float*)d_in[8];
  float* out = (float*)d_out;

  char* ws = (char*)d_ws;
  size_t fixed = ((size_t)KSEG * MDIM * 2 + 255) & ~(size_t)255;  // Ct 640KB

  int NC = NTRAJ;
  while (NC > 8) {
    size_t need = fixed + (size_t)NC * TSTEPS * ((size_t)KSEG * 2 + MDIM * 2);
    if (need <= ws_size) break;
    NC >>= 1;
  }
  const int NTc = NC * TSTEPS;
  f16_t*    Ct = (f16_t*)ws;
  unsigned* Zu = (unsigned*)(ws + fixed);
  f16_t*    M  = (f16_t*)(ws + fixed + (size_t)NTc * KSEG * 2);

  for (int n0 = 0; n0 < NTRAJ; n0 += NC) {
    hipLaunchKernelGGL(build_CtZt, dim3(128 + NTc / 8), dim3(256), 0, stream,
                       A, Wa, ba, Wo, bo, actions, obss, Ct, Zu, n0);
    hipLaunchKernelGGL(gemm_M, dim3((NTc >> 8) * 4), dim3(512), 0, stream,
                       (const f16_t*)Zu, Ct, M, NTc);
    hipLaunchKernelGGL(chainfin, dim3(NC), dim3(1024), 0, stream,
                       M, alpha, Omega, out, n0);
  }
}

// Round 9
// 63.911 us; speedup vs baseline: 4.7912x; 1.0906x over previous
//
#include <hip/hip_runtime.h>

typedef _Float16 f16_t;
typedef f16_t f16x8 __attribute__((ext_vector_type(8)));
typedef f16_t f16x4 __attribute__((ext_vector_type(4)));
typedef float f32x4 __attribute__((ext_vector_type(4)));

#define R_ 32
#define NTRAJ 256
#define TSTEPS 128
#define PDIM 17
#define KTRUE 289
#define KSEG 320          // padded K (5 x 64)
#define NKT 5             // K-tiles
#define MDIM 1024
#define CHS 16            // steps per chain wave
#define NCH 8             // chunks per trajectory

#define SBAR() __builtin_amdgcn_s_barrier()
#define SCHED0() __builtin_amdgcn_sched_barrier(0)
#define PRIO(x) __builtin_amdgcn_s_setprio(x)

// ---------------------------------------------------------------------------
// Merged prep kernel. Blocks [0,128): Ct[il][pq] (fp16, K-contig).
// Blocks [128, 128+NTc/8): Z[nt][KSEG] fp16, Z[nt,pq] = a'[p]*o'[q].
// ---------------------------------------------------------------------------
__global__ __launch_bounds__(256) void build_CtZt(const float* __restrict__ A,
                                                  const float* __restrict__ Wa,
                                                  const float* __restrict__ ba,
                                                  const float* __restrict__ Wo,
                                                  const float* __restrict__ bo,
                                                  const float* __restrict__ actions,
                                                  const float* __restrict__ obss,
                                                  f16_t* __restrict__ Ct,
                                                  unsigned* __restrict__ Z, int n0) {
  __shared__ float Dls[PDIM][32][8];
  __shared__ float Was[PDIM][33];
  __shared__ float Wos[PDIM][33];
  __shared__ float sav[8][PDIM];
  __shared__ float sov[8][PDIM];
  const int tid = threadIdx.x;

  if (blockIdx.x < 128) {
    const int i = blockIdx.x >> 2;
    const int l0 = (blockIdx.x & 3) * 8;
    for (int e = tid; e < PDIM * 32; e += 256) {
      int p = e >> 5, j = e & 31;
      Was[p][j] = (p < 16) ? Wa[p * 32 + j] : ba[j];
      Wos[p][j] = (p < 16) ? Wo[p * 32 + j] : bo[j];
    }
    const int k = tid >> 3, lp = tid & 7;
    float Dreg[PDIM] = {};
    const float* Abase = A + (size_t)i * 32768 + k * 32 + l0 + lp;
    __syncthreads();
#pragma unroll
    for (int j = 0; j < 32; ++j) {
      float a = Abase[(size_t)j * 1024];
#pragma unroll
      for (int p = 0; p < PDIM; ++p) Dreg[p] += Was[p][j] * a;
    }
#pragma unroll
    for (int p = 0; p < PDIM; ++p) Dls[p][k][lp] = Dreg[p];
    __syncthreads();

    for (int v = tid; v < KTRUE * 8; v += 256) {
      int pq = v >> 3, l = v & 7;
      int p = pq / PDIM, q = pq % PDIM;
      float s = 0.f;
#pragma unroll
      for (int kk = 0; kk < 32; ++kk) s += Wos[q][kk] * Dls[p][kk][l];
      Ct[(size_t)(i * 32 + l0 + l) * KSEG + pq] = (f16_t)s;
    }
    for (int v = tid; v < (KSEG - KTRUE) * 8; v += 256) {
      int pq = KTRUE + (v >> 3), l = v & 7;
      Ct[(size_t)(i * 32 + l0 + l) * KSEG + pq] = (f16_t)0.f;
    }
  } else {
    const int zbid = blockIdx.x - 128;
    const int r = tid >> 5;
    const int c = tid & 31;
    const int nt = zbid * 8 + r;
    const size_t gnt = (size_t)n0 * TSTEPS + nt;
    if (c < PDIM) {
      sav[r][c] = (c < 16) ? actions[gnt * 16 + c] : 1.f;
      sov[r][c] = (c < 16) ? obss[gnt * 16 + c] : 1.f;
    }
    __syncthreads();
    unsigned* zr = Z + (size_t)nt * (KSEG / 2);
#pragma unroll
    for (int u = 0; u < 5; ++u) {
      int col = u * 32 + c;
      int k0 = col * 2, k1 = k0 + 1;
      float z0 = (k0 < KTRUE) ? sav[r][k0 / PDIM] * sov[r][k0 % PDIM] : 0.f;
      float z1 = (k1 < KTRUE) ? sav[r][k1 / PDIM] * sov[r][k1 % PDIM] : 0.f;
      unsigned short h0 = __builtin_bit_cast(unsigned short, (f16_t)z0);
      unsigned short h1 = __builtin_bit_cast(unsigned short, (f16_t)z1);
      zr[col] = (unsigned)h0 | ((unsigned)h1 << 16);
    }
  }
}

// ---------------------------------------------------------------------------
// 256x256 8-phase MFMA GEMM (unchanged, verified R5-R8).
// ---------------------------------------------------------------------------
__device__ __forceinline__ void gload16(const void* g, void* lds_) {
  __builtin_amdgcn_global_load_lds(
      (const __attribute__((address_space(1))) void*)g,
      (__attribute__((address_space(3))) void*)lds_, 16, 0, 0);
}

__global__ __launch_bounds__(512, 2) void gemm_M(const f16_t* __restrict__ Z,
                                                 const f16_t* __restrict__ Ct,
                                                 f16_t* __restrict__ Mout, int NTc) {
  __shared__ char lds[131072];
  const int nbm = NTc >> 8;
  const int nwg = nbm * 4;
  const int cpx = nwg >> 3;
  const int bid = blockIdx.x;
  const int wg = (bid & 7) * cpx + (bid >> 3);
  const int bm = (wg >> 2) << 8;
  const int bn = (wg & 3) << 8;

  const int tid = threadIdx.x;
  const int w = tid >> 6, lane = tid & 63;
  const int wr = w >> 2, wc = w & 3;
  const int lrow = lane & 15, lk = lane >> 4;
  const int u0 = lk ^ (lrow & 7);
  const int u1 = (lk + 4) ^ (lrow & 7);

  const int srow = lane >> 3;
  const int jsrc = (lane & 7) ^ srow;
  const char* Zb = (const char*)Z + (size_t)(bm + srow) * (KSEG * 2) + jsrc * 16;
  const char* Cb = (const char*)Ct + (size_t)(bn + srow) * (KSEG * 2) + jsrc * 16;

  auto stageA = [&](char* Ab, int sel, int kt) {
    const size_t ka = (size_t)kt * 128;
#pragma unroll
    for (int r = 0; r < 2; ++r) {
      int e = w * 2 + r;
      int c = sel ? (e + 8 + ((e >= 8) ? 8 : 0)) : (e + ((e >= 8) ? 8 : 0));
      gload16(Zb + (size_t)c * 8 * (KSEG * 2) + ka, Ab + c * 1024);
    }
  };
  auto stageB = [&](char* Bb, int half, int kt) {
    const size_t kb = (size_t)kt * 128;
#pragma unroll
    for (int r = 0; r < 2; ++r) {
      int c = w * 2 + r;
      gload16(Cb + (size_t)(half * 128 + c * 8) * (KSEG * 2) + kb,
              Bb + half * 16384 + c * 1024);
    }
  };

  f32x4 acc[8][4] = {};
  f16x8 af[4][2], bfr[4][2];

  stageA(lds, 0, 0); stageA(lds, 1, 0);
  stageB(lds + 32768, 0, 0); stageB(lds + 32768, 1, 0);
  stageA(lds + 65536, 0, 1); stageA(lds + 65536, 1, 1);
  stageB(lds + 98304, 0, 1); stageB(lds + 98304, 1, 1);
  asm volatile("s_waitcnt vmcnt(8)" ::: "memory"); SCHED0();
  SBAR(); SCHED0();

  for (int kt = 0; kt < NKT; ++kt) {
    const int p = kt & 1;
    char* Ap = lds + (p << 16);
    char* Bp = Ap + 32768;
    const bool doStage = (kt + 2 < NKT);

    // ---- P1 ----
#pragma unroll
    for (int mf = 0; mf < 4; ++mf) {
      const char* rp = Ap + (wr * 128 + mf * 16 + lrow) * 128;
      af[mf][0] = *(const f16x8*)(rp + u0 * 16);
      af[mf][1] = *(const f16x8*)(rp + u1 * 16);
    }
#pragma unroll
    for (int nf = 0; nf < 4; ++nf) {
      const char* cp = Bp + (wc * 64 + nf * 16 + lrow) * 128;
      bfr[nf][0] = *(const f16x8*)(cp + u0 * 16);
      bfr[nf][1] = *(const f16x8*)(cp + u1 * 16);
    }
    SCHED0();
    asm volatile("s_waitcnt lgkmcnt(0)" ::: "memory"); SCHED0();
    SBAR(); SCHED0();
    PRIO(1);
#pragma unroll
    for (int ks = 0; ks < 2; ++ks)
#pragma unroll
      for (int mf = 0; mf < 4; ++mf)
#pragma unroll
        for (int nf = 0; nf < 2; ++nf)
          acc[mf][nf] = __builtin_amdgcn_mfma_f32_16x16x32_f16(af[mf][ks], bfr[nf][ks], acc[mf][nf], 0, 0, 0);
    PRIO(0);
    SCHED0(); SBAR(); SCHED0();

    // ---- P2 ----
    if (doStage) { stageA(Ap, 0, kt + 2); stageB(Bp, 0, kt + 2); stageB(Bp, 1, kt + 2); }
    PRIO(1);
#pragma unroll
    for (int ks = 0; ks < 2; ++ks)
#pragma unroll
      for (int mf = 0; mf < 4; ++mf)
#pragma unroll
        for (int nf = 2; nf < 4; ++nf)
          acc[mf][nf] = __builtin_amdgcn_mfma_f32_16x16x32_f16(af[mf][ks], bfr[nf][ks], acc[mf][nf], 0, 0, 0);
    PRIO(0);
    SCHED0(); SBAR(); SCHED0();

    // ---- P3 ----
#pragma unroll
    for (int mf = 0; mf < 4; ++mf) {
      const char* rp = Ap + (wr * 128 + (mf + 4) * 16 + lrow) * 128;
      af[mf][0] = *(const f16x8*)(rp + u0 * 16);
      af[mf][1] = *(const f16x8*)(rp + u1 * 16);
    }
    SCHED0();
    asm volatile("s_waitcnt lgkmcnt(0)" ::: "memory"); SCHED0();
    SBAR(); SCHED0();
    PRIO(1);
#pragma unroll
    for (int ks = 0; ks < 2; ++ks)
#pragma unroll
      for (int mf = 0; mf < 4; ++mf)
#pragma unroll
        for (int nf = 0; nf < 2; ++nf)
          acc[mf + 4][nf] = __builtin_amdgcn_mfma_f32_16x16x32_f16(af[mf][ks], bfr[nf][ks], acc[mf + 4][nf], 0, 0, 0);
    PRIO(0);
    SCHED0(); SBAR(); SCHED0();

    // ---- P4 ----
    if (doStage) stageA(Ap, 1, kt + 2);
    PRIO(1);
#pragma unroll
    for (int ks = 0; ks < 2; ++ks)
#pragma unroll
      for (int mf = 0; mf < 4; ++mf)
#pragma unroll
        for (int nf = 2; nf < 4; ++nf)
          acc[mf + 4][nf] = __builtin_amdgcn_mfma_f32_16x16x32_f16(af[mf][ks], bfr[nf][ks], acc[mf + 4][nf], 0, 0, 0);
    PRIO(0);
    if (kt <= NKT - 3) {
      asm volatile("s_waitcnt vmcnt(8)" ::: "memory");
    } else if (kt == NKT - 2) {
      asm volatile("s_waitcnt vmcnt(0)" ::: "memory");
    }
    SCHED0(); SBAR(); SCHED0();
  }

#pragma unroll
  for (int mf = 0; mf < 8; ++mf) {
    const int row0 = bm + wr * 128 + mf * 16 + lk * 4;
#pragma unroll
    for (int nf = 0; nf < 4; ++nf) {
      const int col = bn + wc * 64 + nf * 16 + lrow;
#pragma unroll
      for (int r2 = 0; r2 < 4; ++r2)
        Mout[(size_t)(row0 + r2) * MDIM + col] = (f16_t)acc[mf][nf][r2];
    }
  }
}

// ---------------------------------------------------------------------------
// chainfin v2: transposed-chain. 1 block (8 waves) per trajectory; wave w
// computes P_w^T = M_{15}^T * ... * M_0^T (within its 16-step chunk) as
// Q := Q * S_t (S_t = M_t^T): B-frag = row-major M_t read directly (b128),
// M-tiles staged by global_load_lds (triple buffer, per-wave vmcnt(2)),
// NO transpose scatter. Finish folds s = Omega^T; s = s*P_c^T (c=7..0);
// out = sum alpha[i]*s[i].
// ---------------------------------------------------------------------------
__global__ __launch_bounds__(512) void chainfin(const f16_t* __restrict__ M,
                                                const float* __restrict__ alpha,
                                                const float* __restrict__ Omega,
                                                float* __restrict__ out, int n0) {
  __shared__ char wbuf[8][8704];       // per wave: Q [32][80B] @0, Mbuf[3][2048] @2560
  __shared__ f16_t sPc[NCH][1024];     // chunk products P^T, row-major [32][32]
  const int wid = threadIdx.x >> 6, lane = threadIdx.x & 63;
  char* Qb = wbuf[wid];
  char* Mb3 = wbuf[wid] + 2560;
  const char* Ms = (const char*)M + ((size_t)blockIdx.x * TSTEPS + wid * CHS) * 2048;

  const int lr = lane & 15, lg = lane >> 4;

  // ---- Q init: Q = M[15]^T (reg load + one-time scatter transpose) ----
  {
    const int il = lane >> 1, c0 = (lane & 1) << 4;
    const char* mp = Ms + 15 * 2048 + il * 64 + c0 * 2;
    f16x8 va = *(const f16x8*)(mp);
    f16x8 vb = *(const f16x8*)(mp + 16);
#pragma unroll
    for (int j = 0; j < 8; ++j) {
      *(f16_t*)(Qb + (c0 + j) * 80 + il * 2) = va[j];
      *(f16_t*)(Qb + (c0 + 8 + j) * 80 + il * 2) = vb[j];
    }
  }

  // ---- staging: M-tile 2KB = 32 rows x 64B; dest linear, source pre-swizzled
  // swz(r) = (r + (r>>2)) & 3; LDS[row][u] = G[row][u ^ swz(row)]
  const int r0 = lane >> 2, us = lane & 3;
  const int so0 = r0 * 64 + ((us ^ ((r0 + (r0 >> 2)) & 3)) * 16);
  const int r1 = 16 + r0;
  const int so1 = r1 * 64 + ((us ^ ((r1 + (r1 >> 2)) & 3)) * 16);

  auto stageM = [&](int t) {
    const char* src = Ms + (size_t)t * 2048;
    char* dst = Mb3 + (t % 3) * 2048;
    gload16(src + so0, dst + lane * 16);
    gload16(src + so1, dst + 1024 + lane * 16);
  };

  // B-frag read offsets (swizzled): row n, unit lg ^ swz(n)
  const int bo0 = lr * 64 + ((lg ^ ((lr + (lr >> 2)) & 3)) * 16);
  const int n1 = 16 + lr;
  const int bo1 = n1 * 64 + ((lg ^ ((n1 + (n1 >> 2)) & 3)) * 16);
  const int ao0 = lr * 80 + lg * 16;
  const int ao1 = (16 + lr) * 80 + lg * 16;

  stageM(14); stageM(13);   // 2-deep prefetch (4 outstanding)

  const f32x4 z = {0.f, 0.f, 0.f, 0.f};
  for (int t = 14; t >= 0; --t) {
    if (t > 0) { asm volatile("s_waitcnt vmcnt(2)" ::: "memory"); }
    else       { asm volatile("s_waitcnt vmcnt(0)" ::: "memory"); }
    const char* Mt = Mb3 + (t % 3) * 2048;
    f16x8 bf0 = *(const f16x8*)(Mt + bo0);
    f16x8 bf1 = *(const f16x8*)(Mt + bo1);
    f16x8 af0 = *(const f16x8*)(Qb + ao0);
    f16x8 af1 = *(const f16x8*)(Qb + ao1);
    if (t >= 2) stageM(t - 2);
    f32x4 d00 = __builtin_amdgcn_mfma_f32_16x16x32_f16(af0, bf0, z, 0, 0, 0);
    f32x4 d01 = __builtin_amdgcn_mfma_f32_16x16x32_f16(af0, bf1, z, 0, 0, 0);
    f32x4 d10 = __builtin_amdgcn_mfma_f32_16x16x32_f16(af1, bf0, z, 0, 0, 0);
    f32x4 d11 = __builtin_amdgcn_mfma_f32_16x16x32_f16(af1, bf1, z, 0, 0, 0);
    if (t > 0) {
      // write back Q: D layout col=lr, row=lg*4+r2 (+16 halves)
#pragma unroll
      for (int r2 = 0; r2 < 4; ++r2) {
        *(f16_t*)(Qb + (lg * 4 + r2) * 80 + lr * 2)             = (f16_t)d00[r2];
        *(f16_t*)(Qb + (lg * 4 + r2) * 80 + (16 + lr) * 2)      = (f16_t)d01[r2];
        *(f16_t*)(Qb + (16 + lg * 4 + r2) * 80 + lr * 2)        = (f16_t)d10[r2];
        *(f16_t*)(Qb + (16 + lg * 4 + r2) * 80 + (16 + lr) * 2) = (f16_t)d11[r2];
      }
    } else {
      f16_t* pc = sPc[wid];
#pragma unroll
      for (int r2 = 0; r2 < 4; ++r2) {
        pc[(lg * 4 + r2) * 32 + lr]           = (f16_t)d00[r2];
        pc[(lg * 4 + r2) * 32 + 16 + lr]      = (f16_t)d01[r2];
        pc[(16 + lg * 4 + r2) * 32 + lr]      = (f16_t)d10[r2];
        pc[(16 + lg * 4 + r2) * 32 + 16 + lr] = (f16_t)d11[r2];
      }
    }
  }
  __syncthreads();

  if (wid == 0) {
    const int ig = lane >> 3, lgf = lane & 7;
    float s0 = Omega[ig * 4 + 0], s1 = Omega[ig * 4 + 1];
    float s2 = Omega[ig * 4 + 2], s3 = Omega[ig * 4 + 3];
    for (int c = NCH - 1; c >= 0; --c) {
      const f16_t* pn = &sPc[c][ig * 128 + lgf * 4];
      f32x4 part = __builtin_convertvector(*(const f16x4*)(pn), f32x4) * s0;
      part += __builtin_convertvector(*(const f16x4*)(pn + 32), f32x4) * s1;
      part += __builtin_convertvector(*(const f16x4*)(pn + 64), f32x4) * s2;
      part += __builtin_convertvector(*(const f16x4*)(pn + 96), f32x4) * s3;
      float p0 = part[0], p1 = part[1], p2 = part[2], p3 = part[3];
      p0 += __shfl_down(p0, 8, 64);  p1 += __shfl_down(p1, 8, 64);
      p2 += __shfl_down(p2, 8, 64);  p3 += __shfl_down(p3, 8, 64);
      p0 += __shfl_down(p0, 16, 64); p1 += __shfl_down(p1, 16, 64);
      p2 += __shfl_down(p2, 16, 64); p3 += __shfl_down(p3, 16, 64);
      p0 += __shfl_down(p0, 32, 64); p1 += __shfl_down(p1, 32, 64);
      p2 += __shfl_down(p2, 32, 64); p3 += __shfl_down(p3, 32, 64);
      s0 = __shfl(p0, ig, 64); s1 = __shfl(p1, ig, 64);
      s2 = __shfl(p2, ig, 64); s3 = __shfl(p3, ig, 64);
    }
    float v = 0.f;
    if (lgf == 0)
      v = s0 * alpha[ig * 4 + 0] + s1 * alpha[ig * 4 + 1] +
          s2 * alpha[ig * 4 + 2] + s3 * alpha[ig * 4 + 3];
    v += __shfl_down(v, 32, 64);
    v += __shfl_down(v, 16, 64);
    v += __shfl_down(v, 8, 64);
    if (lane == 0) out[n0 + blockIdx.x] = v;
  }
}

// ---------------------------------------------------------------------------
extern "C" void kernel_launch(void* const* d_in, const int* in_sizes, int n_in,
                              void* d_out, int out_size, void* d_ws, size_t ws_size,
                              hipStream_t stream) {
  const float* actions = (const float*)d_in[0];
  const float* obss    = (const float*)d_in[1];
  const float* Wa      = (const float*)d_in[2];
  const float* ba      = (const float*)d_in[3];
  const float* Wo      = (const float*)d_in[4];
  const float* bo      = (const float*)d_in[5];
  const float* alpha   = (const float*)d_in[6];
  const float* A       = (const float*)d_in[7];
  const float* Omega   = (const float*)d_in[8];
  float* out = (float*)d_out;

  char* ws = (char*)d_ws;
  size_t fixed = ((size_t)KSEG * MDIM * 2 + 255) & ~(size_t)255;  // Ct 640KB

  int NC = NTRAJ;
  while (NC > 8) {
    size_t need = fixed + (size_t)NC * TSTEPS * ((size_t)KSEG * 2 + MDIM * 2);
    if (need <= ws_size) break;
    NC >>= 1;
  }
  const int NTc = NC * TSTEPS;
  f16_t*    Ct = (f16_t*)ws;
  unsigned* Zu = (unsigned*)(ws + fixed);
  f16_t*    M  = (f16_t*)(ws + fixed + (size_t)NTc * KSEG * 2);

  for (int n0 = 0; n0 < NTRAJ; n0 += NC) {
    hipLaunchKernelGGL(build_CtZt, dim3(128 + NTc / 8), dim3(256), 0, stream,
                       A, Wa, ba, Wo, bo, actions, obss, Ct, Zu, n0);
    hipLaunchKernelGGL(gemm_M, dim3((NTc >> 8) * 4), dim3(512), 0, stream,
                       (const f16_t*)Zu, Ct, M, NTc);
    hipLaunchKernelGGL(chainfin, dim3(NC), dim3(512), 0, stream,
                       M, alpha, Omega, out, n0);
  }
}